// Round 2
// baseline (779.463 us; speedup 1.0000x reference)
//
#include <hip/hip_runtime.h>
#include <hip/hip_bf16.h>
#include <math.h>

using bf16 = __hip_bfloat16;

#define LEAKY 0.2f
#define BN_EPS 1e-5f
#define NEGBIG -1e30f

__device__ __forceinline__ float lrelu(float z){ return z > 0.f ? z : LEAKY * z; }

// dtype-adaptive load: isbf=1 -> bf16, else fp32
__device__ __forceinline__ float ldf(const void* p, size_t i, int isbf){
  if (isbf) return (float)((const bf16*)p)[i];
  return ((const float*)p)[i];
}

// ---------------- input dtype detector ----------------
// Samples W1 (~N(0,0.01)). bf16 bit patterns have exponent field in [64,140]
// essentially always; fp32 low-half uint16s are ~uniform (~30% hit rate).
__global__ void detect_dtype(const unsigned short* __restrict__ w1bits, int* flag){
  __shared__ int cntr;
  if (threadIdx.x == 0) cntr = 0;
  __syncthreads();
  unsigned u = w1bits[threadIdx.x * 2];
  int e = (u >> 7) & 0xff;
  atomicAdd(&cntr, (e >= 64 && e <= 140) ? 1 : 0);
  __syncthreads();
  if (threadIdx.x == 0) *flag = (cntr >= 160) ? 1 : 0;
}

// ---------------- CSR build (dst-grouped, order-free segments) ----------------
__global__ void csr_init(int* cnt, int* total, int n){
  int g = blockIdx.x*256 + threadIdx.x;
  if (g < n) cnt[g] = 1;            // self loop
  if (g == 0) *total = 0;
}
__global__ void csr_count(const int* __restrict__ dst, int* cnt, int e, int n){
  int g = blockIdx.x*256 + threadIdx.x;
  if (g < e){
    int d = dst[g];
    if ((unsigned)d < (unsigned)n) atomicAdd(&cnt[d], 1);
  }
}
__global__ void csr_scan(const int* __restrict__ cnt, int* start, int* total, int n){
  __shared__ int s[256];
  __shared__ int base_s;
  int t = threadIdx.x;
  int g = blockIdx.x*256 + t;
  int v = (g < n) ? cnt[g] : 0;
  s[t] = v;
  __syncthreads();
  for (int off = 1; off < 256; off <<= 1){
    int x = (t >= off) ? s[t-off] : 0;
    __syncthreads();
    s[t] += x;
    __syncthreads();
  }
  if (t == 255) base_s = atomicAdd(total, s[255]);
  __syncthreads();
  if (g < n) start[g] = base_s + s[t] - v;
}
__global__ void csr_self(const int* __restrict__ start, int* cursor, int* col, int n){
  int g = blockIdx.x*256 + threadIdx.x;
  if (g < n){ int p = start[g]; col[p] = g; cursor[g] = p + 1; }
}
__global__ void csr_fill(const int* __restrict__ src, const int* __restrict__ dst,
                         int* cursor, int* col, int e, int n){
  int g = blockIdx.x*256 + threadIdx.x;
  if (g < e){
    int d = dst[g];
    if ((unsigned)d < (unsigned)n){
      int p = atomicAdd(&cursor[d], 1);
      col[p] = src[g];
    }
  }
}

// ---------------- GEMM 128x128 + fused al_src/al_dst (layers 1,2) ----------------
// block = 256 threads, 64 nodes/block; thread = 4 nodes x 8 channels.
// Wl: fp32 K-chunk [64][128] 32KB; xs: fp32 transposed [k][node] swizzled 32KB.
__global__ __launch_bounds__(256) void gemm_al(
    const void* __restrict__ X, int xraw,
    const void* __restrict__ W, const void* __restrict__ Wsrc, const void* __restrict__ Wdst,
    const int* __restrict__ flagp,
    float* __restrict__ H, float* __restrict__ AL, float* __restrict__ AD, int n)
{
  __shared__ __align__(16) float Wl[64*128];
  __shared__ __align__(16) float xs[128*64];
  const int isbf = *flagp;
  const int t  = threadIdx.x;
  const int nb = blockIdx.x * 64;
  for (int idx = t; idx < 64*128; idx += 256){
    int node = idx >> 7, k = idx & 127;
    int g = nb + node;
    float v = 0.f;
    if (g < n){
      size_t o = (size_t)g*128 + k;
      v = xraw ? ldf(X, o, isbf) : ((const float*)X)[o];
    }
    xs[k*64 + ((node + k) & 63)] = v;   // swizzle: write & read both conflict-free
  }
  const int jg = t & 15, ng = t >> 4;
  const int j0 = jg * 8;
  const int n4 = ng * 4;
  float acc[4][8];
  #pragma unroll
  for (int i = 0; i < 4; ++i)
    #pragma unroll
    for (int u = 0; u < 8; ++u) acc[i][u] = 0.f;

  for (int kc = 0; kc < 128; kc += 64){
    __syncthreads();
    for (int idx = t; idx < 64*128; idx += 256)
      Wl[idx] = ldf(W, (size_t)(kc + (idx >> 7))*128 + (idx & 127), isbf);
    __syncthreads();
    for (int kk = 0; kk < 64; ++kk){
      int k = kc + kk;
      float4 wa = *((const float4*)&Wl[kk*128 + j0]);
      float4 wb = *((const float4*)&Wl[kk*128 + j0 + 4]);
      float w[8] = {wa.x, wa.y, wa.z, wa.w, wb.x, wb.y, wb.z, wb.w};
      float xv[4];
      #pragma unroll
      for (int i = 0; i < 4; ++i) xv[i] = xs[k*64 + ((n4 + i + k) & 63)];
      #pragma unroll
      for (int i = 0; i < 4; ++i)
        #pragma unroll
        for (int u = 0; u < 8; ++u) acc[i][u] += xv[i] * w[u];
    }
  }

  float av[8], dv[8];
  #pragma unroll
  for (int u = 0; u < 8; ++u){ av[u] = ldf(Wsrc, j0+u, isbf); dv[u] = ldf(Wdst, j0+u, isbf); }
  const int head = jg >> 2;
  #pragma unroll
  for (int i = 0; i < 4; ++i){
    int g = nb + n4 + i;
    float ps = 0.f, pd = 0.f;
    #pragma unroll
    for (int u = 0; u < 8; ++u){ ps += acc[i][u]*av[u]; pd += acc[i][u]*dv[u]; }
    ps += __shfl_xor(ps, 1); ps += __shfl_xor(ps, 2);   // 4 lanes of one head
    pd += __shfl_xor(pd, 1); pd += __shfl_xor(pd, 2);
    if (g < n){
      float4 h0 = make_float4(acc[i][0],acc[i][1],acc[i][2],acc[i][3]);
      float4 h1 = make_float4(acc[i][4],acc[i][5],acc[i][6],acc[i][7]);
      *((float4*)&H[(size_t)g*128 + j0])     = h0;
      *((float4*)&H[(size_t)g*128 + j0 + 4]) = h1;
      if ((jg & 3) == 0){ AL[g*4 + head] = ps; AD[g*4 + head] = pd; }
    }
  }
}

// ---------------- GEMM 128x40 + fused al (layer 3, 1 head) ----------------
__global__ __launch_bounds__(256) void gemm3(
    const float* __restrict__ X, const void* __restrict__ W,
    const void* __restrict__ Wsrc, const void* __restrict__ Wdst,
    const int* __restrict__ flagp,
    float* __restrict__ H3, float* __restrict__ AL, float* __restrict__ AD, int n)
{
  __shared__ __align__(16) float Wl[128*41];
  __shared__ __align__(16) float xs[128*64];
  const int isbf = *flagp;
  const int t  = threadIdx.x;
  const int nb = blockIdx.x * 64;
  for (int idx = t; idx < 5120; idx += 256){
    int k = idx / 40, j = idx - k*40;
    Wl[k*41 + j] = ldf(W, idx, isbf);
  }
  for (int idx = t; idx < 64*128; idx += 256){
    int node = idx >> 7, k = idx & 127;
    int g = nb + node;
    float v = 0.f;
    if (g < n) v = X[(size_t)g*128 + k];
    xs[k*64 + ((node + k) & 63)] = v;
  }
  __syncthreads();
  const int jq = t & 7, ng = t >> 3;   // 8 ch-groups x 32 node-groups(2 nodes)
  const int j0 = jq * 5;
  const int n2 = ng * 2;
  float acc[2][5] = {};
  for (int k = 0; k < 128; ++k){
    float w[5];
    #pragma unroll
    for (int u = 0; u < 5; ++u) w[u] = Wl[k*41 + j0 + u];
    float x0 = xs[k*64 + ((n2 + k) & 63)];
    float x1 = xs[k*64 + ((n2 + 1 + k) & 63)];
    #pragma unroll
    for (int u = 0; u < 5; ++u){ acc[0][u] += x0*w[u]; acc[1][u] += x1*w[u]; }
  }
  float av[5], dv[5];
  #pragma unroll
  for (int u = 0; u < 5; ++u){ av[u] = ldf(Wsrc, j0+u, isbf); dv[u] = ldf(Wdst, j0+u, isbf); }
  #pragma unroll
  for (int i = 0; i < 2; ++i){
    int g = nb + n2 + i;
    float ps = 0.f, pd = 0.f;
    #pragma unroll
    for (int u = 0; u < 5; ++u){ ps += acc[i][u]*av[u]; pd += acc[i][u]*dv[u]; }
    ps += __shfl_xor(ps,1); ps += __shfl_xor(ps,2); ps += __shfl_xor(ps,4);
    pd += __shfl_xor(pd,1); pd += __shfl_xor(pd,2); pd += __shfl_xor(pd,4);
    if (g < n){
      #pragma unroll
      for (int u = 0; u < 5; ++u) H3[(size_t)g*40 + j0 + u] = acc[i][u];
      if (jq == 0){ AL[g] = ps; AD[g] = pd; }
    }
  }
}

// ---------------- per-dst online softmax stats ----------------
__device__ __forceinline__ void osm(float z, float& m, float& l){
  if (z > m){ l = l*__expf(m - z) + 1.f; m = z; }
  else        l += __expf(z - m);
}
__global__ void stats4(const float4* __restrict__ AL4, const float4* __restrict__ AD4,
                       const int* __restrict__ cnt, const int* __restrict__ start,
                       const int* __restrict__ col,
                       float4* __restrict__ M4, float4* __restrict__ RL4, int n)
{
  int g = blockIdx.x*256 + threadIdx.x;
  if (g >= n) return;
  float4 ad = AD4[g];
  float m0=NEGBIG,m1=NEGBIG,m2=NEGBIG,m3=NEGBIG;
  float l0=0.f,l1=0.f,l2=0.f,l3=0.f;
  int base = start[g], deg = cnt[g];
  for (int i = 0; i < deg; ++i){
    int s = col[base + i];
    if ((unsigned)s >= (unsigned)n) continue;
    float4 as = AL4[s];
    osm(lrelu(as.x + ad.x), m0, l0);
    osm(lrelu(as.y + ad.y), m1, l1);
    osm(lrelu(as.z + ad.z), m2, l2);
    osm(lrelu(as.w + ad.w), m3, l3);
  }
  M4[g]  = make_float4(m0,m1,m2,m3);
  RL4[g] = make_float4(1.f/l0, 1.f/l1, 1.f/l2, 1.f/l3);
}
__global__ void stats1(const float* __restrict__ AL, const float* __restrict__ AD,
                       const int* __restrict__ cnt, const int* __restrict__ start,
                       const int* __restrict__ col,
                       float* __restrict__ M, float* __restrict__ RL, int n)
{
  int g = blockIdx.x*256 + threadIdx.x;
  if (g >= n) return;
  float ad = AD[g];
  float m = NEGBIG, l = 0.f;
  int base = start[g], deg = cnt[g];
  for (int i = 0; i < deg; ++i){
    int s = col[base + i];
    if ((unsigned)s >= (unsigned)n) continue;
    osm(lrelu(AL[s] + ad), m, l);
  }
  M[g] = m; RL[g] = 1.f/l;
}

// ---------------- aggregation: wave per node, lanes = channels ----------------
__global__ __launch_bounds__(256) void agg4(
    const float* __restrict__ H,
    const float4* __restrict__ AL4, const float4* __restrict__ AD4,
    const float4* __restrict__ M4,  const float4* __restrict__ RL4,
    const int* __restrict__ cnt, const int* __restrict__ start, const int* __restrict__ col,
    const void* __restrict__ bias, const void* __restrict__ bng, const void* __restrict__ bnb,
    const void* __restrict__ bnm,  const void* __restrict__ bnv,
    const int* __restrict__ flagp,
    float* __restrict__ Hout, int n)
{
  const int isbf = *flagp;
  const int wave = threadIdx.x >> 6;
  const int lane = threadIdx.x & 63;
  const int node = blockIdx.x*4 + wave;
  if (node >= n) return;
  float4 ad = AD4[node], m4 = M4[node], rl4 = RL4[node];
  const bool lo = lane < 32;
  const float ad0 = lo ? ad.x  : ad.y,  ad1 = lo ? ad.z  : ad.w;
  const float mm0 = lo ? m4.x  : m4.y,  mm1 = lo ? m4.z  : m4.w;
  const float rr0 = lo ? rl4.x : rl4.y, rr1 = lo ? rl4.z : rl4.w;
  const int c0 = lane, c1 = lane + 64;
  float acc0 = 0.f, acc1 = 0.f;
  const int base = start[node], deg = cnt[node];
  for (int i = 0; i < deg; ++i){
    int s = col[base + i];
    if ((unsigned)s >= (unsigned)n) continue;
    float4 as = AL4[s];
    float as0 = lo ? as.x : as.y;
    float as1 = lo ? as.z : as.w;
    float w0 = __expf(lrelu(as0 + ad0) - mm0) * rr0;
    float w1 = __expf(lrelu(as1 + ad1) - mm1) * rr1;
    const float* hp = H + (size_t)s*128;
    acc0 += w0 * hp[c0];
    acc1 += w1 * hp[c1];
  }
  // epilogue: + bias, relu, BN(eval)
  {
    float v = fmaxf(acc0 + ldf(bias,c0,isbf), 0.f);
    v = (v - ldf(bnm,c0,isbf)) * rsqrtf(ldf(bnv,c0,isbf) + BN_EPS) * ldf(bng,c0,isbf) + ldf(bnb,c0,isbf);
    Hout[(size_t)node*128 + c0] = v;
  }
  {
    float v = fmaxf(acc1 + ldf(bias,c1,isbf), 0.f);
    v = (v - ldf(bnm,c1,isbf)) * rsqrtf(ldf(bnv,c1,isbf) + BN_EPS) * ldf(bng,c1,isbf) + ldf(bnb,c1,isbf);
    Hout[(size_t)node*128 + c1] = v;
  }
}

__global__ __launch_bounds__(256) void agg1(
    const float* __restrict__ H3,
    const float* __restrict__ AL, const float* __restrict__ AD,
    const float* __restrict__ M,  const float* __restrict__ RL,
    const int* __restrict__ cnt, const int* __restrict__ start, const int* __restrict__ col,
    const void* __restrict__ b3, const int* __restrict__ flagp,
    void* __restrict__ out, int n)
{
  const int isbf = *flagp;
  const int wave = threadIdx.x >> 6;
  const int lane = threadIdx.x & 63;
  const int node = blockIdx.x*4 + wave;
  if (node >= n) return;
  const float ad = AD[node], m = M[node], rl = RL[node];
  const bool act = lane < 40;
  float acc = 0.f;
  const int base = start[node], deg = cnt[node];
  for (int i = 0; i < deg; ++i){
    int s = col[base + i];
    if ((unsigned)s >= (unsigned)n) continue;
    float w = __expf(lrelu(AL[s] + ad) - m) * rl;
    float hv = act ? H3[(size_t)s*40 + lane] : 0.f;
    acc += w * hv;
  }
  float z = act ? (acc + ldf(b3, lane < 40 ? lane : 0, isbf)) : NEGBIG;
  // log_softmax across the 40 active lanes
  float mx = z;
  #pragma unroll
  for (int off = 1; off < 64; off <<= 1) mx = fmaxf(mx, __shfl_xor(mx, off));
  float p = act ? __expf(z - mx) : 0.f;
  float sum = p;
  #pragma unroll
  for (int off = 1; off < 64; off <<= 1) sum += __shfl_xor(sum, off);
  if (act){
    float r = z - mx - __logf(sum);
    if (isbf) ((bf16*)out)[(size_t)node*40 + lane] = __float2bfloat16(r);
    else      ((float*)out)[(size_t)node*40 + lane] = r;
  }
}

// ---------------- launch ----------------
extern "C" void kernel_launch(void* const* d_in, const int* in_sizes, int n_in,
                              void* d_out, int out_size, void* d_ws, size_t ws_size,
                              hipStream_t stream)
{
  (void)n_in; (void)out_size; (void)ws_size;
  const void* x    = d_in[0];
  const int*  ei   = (const int*)d_in[1];
  const void* W1   = d_in[2];
  const void* as1  = d_in[3];
  const void* ad1  = d_in[4];
  const void* b1   = d_in[5];
  const void* W2   = d_in[6];
  const void* as2  = d_in[7];
  const void* ad2  = d_in[8];
  const void* b2   = d_in[9];
  const void* W3   = d_in[10];
  const void* as3  = d_in[11];
  const void* ad3  = d_in[12];
  const void* b3   = d_in[13];
  const void* bn1g = d_in[14];
  const void* bn1b = d_in[15];
  const void* bn1m = d_in[16];
  const void* bn1v = d_in[17];
  const void* bn2g = d_in[18];
  const void* bn2b = d_in[19];
  const void* bn2m = d_in[20];
  const void* bn2v = d_in[21];

  const int N  = in_sizes[0] / 128;
  const int E  = in_sizes[1] / 2;
  const int ET = E + N;

  char* w = (char*)d_ws;
  size_t off = 0;
  auto alloc = [&](size_t bytes)->char*{
    char* p = w + off; off = (off + bytes + 255) & ~(size_t)255; return p;
  };
  float* HA   = (float*)alloc((size_t)N*128*4);  // also aliased as H3 in layer 3
  float* HB   = (float*)alloc((size_t)N*128*4);
  float* AL   = (float*)alloc((size_t)N*4*4);
  float* AD   = (float*)alloc((size_t)N*4*4);
  float* M    = (float*)alloc((size_t)N*4*4);
  float* RL   = (float*)alloc((size_t)N*4*4);
  int*   cnt    = (int*)alloc((size_t)N*4);
  int*   start  = (int*)alloc((size_t)N*4);
  int*   cursor = (int*)alloc((size_t)N*4);
  int*   col    = (int*)alloc((size_t)ET*4);
  int*   flag   = (int*)alloc(256);
  int*   total  = (int*)alloc(256);
  float* H3   = HA;   // HA is dead by the time layer-3 gemm writes H3

  const int* srcp = ei;
  const int* dstp = ei + E;

  const int nb256 = (N + 255)/256, eb256 = (E + 255)/256;
  const int gb = (N + 63)/64, bb = (N + 3)/4;

  detect_dtype<<<1,256,0,stream>>>((const unsigned short*)W1, flag);

  csr_init <<<nb256,256,0,stream>>>(cnt, total, N);
  csr_count<<<eb256,256,0,stream>>>(dstp, cnt, E, N);
  csr_scan <<<nb256,256,0,stream>>>(cnt, start, total, N);
  csr_self <<<nb256,256,0,stream>>>(start, cursor, col, N);
  csr_fill <<<eb256,256,0,stream>>>(srcp, dstp, cursor, col, E, N);

  // layer 1
  gemm_al<<<gb,256,0,stream>>>(x, 1, W1, as1, ad1, flag, HA, AL, AD, N);
  stats4<<<nb256,256,0,stream>>>((const float4*)AL,(const float4*)AD,cnt,start,col,
                                 (float4*)M,(float4*)RL,N);
  agg4<<<bb,256,0,stream>>>(HA,(const float4*)AL,(const float4*)AD,(const float4*)M,
                            (const float4*)RL,cnt,start,col,
                            b1,bn1g,bn1b,bn1m,bn1v,flag,HB,N);
  // layer 2
  gemm_al<<<gb,256,0,stream>>>(HB, 0, W2, as2, ad2, flag, HA, AL, AD, N);
  stats4<<<nb256,256,0,stream>>>((const float4*)AL,(const float4*)AD,cnt,start,col,
                                 (float4*)M,(float4*)RL,N);
  agg4<<<bb,256,0,stream>>>(HA,(const float4*)AL,(const float4*)AD,(const float4*)M,
                            (const float4*)RL,cnt,start,col,
                            b2,bn2g,bn2b,bn2m,bn2v,flag,HB,N);
  // layer 3
  gemm3<<<gb,256,0,stream>>>(HB, W3, as3, ad3, flag, H3, AL, AD, N);
  stats1<<<nb256,256,0,stream>>>(AL, AD, cnt, start, col, M, RL, N);
  agg1<<<bb,256,0,stream>>>(H3, AL, AD, M, RL, cnt, start, col, b3, flag, d_out, N);
}

// Round 3
// 677.297 us; speedup vs baseline: 1.1508x; 1.1508x over previous
//
#include <hip/hip_runtime.h>
#include <hip/hip_bf16.h>
#include <math.h>

using bf16 = __hip_bfloat16;

#define LEAKY 0.2f
#define BN_EPS 1e-5f
#define NEGBIG -1e30f

__device__ __forceinline__ float lrelu(float z){ return z > 0.f ? z : LEAKY * z; }
__device__ __forceinline__ float bflo(unsigned u){ return __uint_as_float(u << 16); }
__device__ __forceinline__ float bfhi(unsigned u){ return __uint_as_float(u & 0xffff0000u); }
// pack two floats into bf16 pair (RNE)
__device__ __forceinline__ unsigned pk(float a, float b){
  unsigned ua = __float_as_uint(a), ub = __float_as_uint(b);
  ua += 0x7fffu + ((ua >> 16) & 1u);
  ub += 0x7fffu + ((ub >> 16) & 1u);
  return (ua >> 16) | (ub & 0xffff0000u);
}
// dtype-adaptive load: isbf=1 -> bf16, else fp32
__device__ __forceinline__ float ldf(const void* p, size_t i, int isbf){
  if (isbf) return (float)((const bf16*)p)[i];
  return ((const float*)p)[i];
}

// ---------------- input dtype detector (samples W1 bit patterns) ----------------
__global__ void detect_dtype(const unsigned short* __restrict__ w1bits, int* flag){
  __shared__ int cntr;
  if (threadIdx.x == 0) cntr = 0;
  __syncthreads();
  unsigned u = w1bits[threadIdx.x * 2];
  int e = (u >> 7) & 0xff;
  atomicAdd(&cntr, (e >= 64 && e <= 140) ? 1 : 0);
  __syncthreads();
  if (threadIdx.x == 0) *flag = (cntr >= 160) ? 1 : 0;
}

// ---------------- CSR build (dst-grouped, order-free segments) ----------------
__global__ void csr_init(int* cnt, int* total, int n){
  int g = blockIdx.x*256 + threadIdx.x;
  if (g < n) cnt[g] = 1;            // self loop
  if (g == 0) *total = 0;
}
__global__ void csr_count(const int* __restrict__ dst, int* cnt, int e, int n){
  int g = blockIdx.x*256 + threadIdx.x;
  if (g < e){
    int d = dst[g];
    if ((unsigned)d < (unsigned)n) atomicAdd(&cnt[d], 1);
  }
}
__global__ void csr_scan(const int* __restrict__ cnt, int* start, int* total, int n){
  __shared__ int s[256];
  __shared__ int base_s;
  int t = threadIdx.x;
  int g = blockIdx.x*256 + t;
  int v = (g < n) ? cnt[g] : 0;
  s[t] = v;
  __syncthreads();
  for (int off = 1; off < 256; off <<= 1){
    int x = (t >= off) ? s[t-off] : 0;
    __syncthreads();
    s[t] += x;
    __syncthreads();
  }
  if (t == 255) base_s = atomicAdd(total, s[255]);
  __syncthreads();
  if (g < n) start[g] = base_s + s[t] - v;
}
__global__ void csr_self(const int* __restrict__ start, int* cursor, int* col, int n){
  int g = blockIdx.x*256 + threadIdx.x;
  if (g < n){ int p = start[g]; col[p] = g; cursor[g] = p + 1; }
}
__global__ void csr_fill(const int* __restrict__ src, const int* __restrict__ dst,
                         int* cursor, int* col, int e, int n){
  int g = blockIdx.x*256 + threadIdx.x;
  if (g < e){
    int d = dst[g];
    if ((unsigned)d < (unsigned)n){
      int p = atomicAdd(&cursor[d], 1);
      col[p] = src[g];
    }
  }
}

// ---------------- GEMM 128x128 + fused al_src/al_dst (layers 1,2) ----------------
// block = 256 threads, 64 nodes/block; thread = 4 nodes x 8 channels.
// Output H2: packed bf16 pairs, [node][64] uints.
// xkind: 0 = external input (dtype per flag), 1 = internal packed bf16 pairs.
__global__ __launch_bounds__(256) void gemm_al(
    const void* __restrict__ X, int xkind,
    const void* __restrict__ W, const void* __restrict__ Wsrc, const void* __restrict__ Wdst,
    const int* __restrict__ flagp,
    unsigned* __restrict__ H2, float* __restrict__ AL, float* __restrict__ AD, int n)
{
  __shared__ __align__(16) float Wl[64*128];
  __shared__ __align__(16) float xs[128*64];
  const int isbf = *flagp;
  const int t  = threadIdx.x;
  const int nb = blockIdx.x * 64;
  const bool pairs = (xkind == 1) || isbf;  // bf16 raw rows == packed pair layout
  for (int idx = t; idx < 64*64; idx += 256){
    int nodeI = idx >> 6, cp = idx & 63;
    int g = nb + nodeI;
    float v0 = 0.f, v1 = 0.f;
    if (g < n){
      if (pairs){
        unsigned u = ((const unsigned*)X)[(size_t)g*64 + cp];
        v0 = bflo(u); v1 = bfhi(u);
      } else {
        float2 f = ((const float2*)X)[(size_t)g*64 + cp];
        v0 = f.x; v1 = f.y;
      }
    }
    int c0 = 2*cp;
    xs[c0*64 + ((nodeI + c0) & 63)] = v0;
    xs[(c0+1)*64 + ((nodeI + c0 + 1) & 63)] = v1;
  }
  const int jg = t & 15, ng = t >> 4;
  const int j0 = jg * 8;
  const int n4 = ng * 4;
  float acc[4][8];
  #pragma unroll
  for (int i = 0; i < 4; ++i)
    #pragma unroll
    for (int u = 0; u < 8; ++u) acc[i][u] = 0.f;

  for (int kc = 0; kc < 128; kc += 64){
    __syncthreads();
    for (int idx = t; idx < 64*128; idx += 256)
      Wl[idx] = ldf(W, (size_t)(kc + (idx >> 7))*128 + (idx & 127), isbf);
    __syncthreads();
    for (int kk = 0; kk < 64; ++kk){
      int k = kc + kk;
      float4 wa = *((const float4*)&Wl[kk*128 + j0]);
      float4 wb = *((const float4*)&Wl[kk*128 + j0 + 4]);
      float w[8] = {wa.x, wa.y, wa.z, wa.w, wb.x, wb.y, wb.z, wb.w};
      float xv[4];
      #pragma unroll
      for (int i = 0; i < 4; ++i) xv[i] = xs[k*64 + ((n4 + i + k) & 63)];
      #pragma unroll
      for (int i = 0; i < 4; ++i)
        #pragma unroll
        for (int u = 0; u < 8; ++u) acc[i][u] += xv[i] * w[u];
    }
  }

  float av[8], dv[8];
  #pragma unroll
  for (int u = 0; u < 8; ++u){ av[u] = ldf(Wsrc, j0+u, isbf); dv[u] = ldf(Wdst, j0+u, isbf); }
  const int head = jg >> 2;
  #pragma unroll
  for (int i = 0; i < 4; ++i){
    int g = nb + n4 + i;
    float ps = 0.f, pd = 0.f;
    #pragma unroll
    for (int u = 0; u < 8; ++u){ ps += acc[i][u]*av[u]; pd += acc[i][u]*dv[u]; }
    ps += __shfl_xor(ps, 1); ps += __shfl_xor(ps, 2);   // 4 lanes of one head
    pd += __shfl_xor(pd, 1); pd += __shfl_xor(pd, 2);
    if (g < n){
      uint4 hq;
      hq.x = pk(acc[i][0], acc[i][1]);
      hq.y = pk(acc[i][2], acc[i][3]);
      hq.z = pk(acc[i][4], acc[i][5]);
      hq.w = pk(acc[i][6], acc[i][7]);
      *((uint4*)&H2[(size_t)g*64 + jg*4]) = hq;
      if ((jg & 3) == 0){ AL[g*4 + head] = ps; AD[g*4 + head] = pd; }
    }
  }
}

// ---------------- GEMM 128x40 + fused al (layer 3, 1 head) ----------------
// block = 256: 4 ch-groups x 10 ch, 64 nodes. Output H3: packed bf16 [node][20] uints.
__global__ __launch_bounds__(256) void gemm3(
    const unsigned* __restrict__ X2, const void* __restrict__ W,
    const void* __restrict__ Wsrc, const void* __restrict__ Wdst,
    const int* __restrict__ flagp,
    unsigned* __restrict__ H3, float* __restrict__ AL, float* __restrict__ AD, int n)
{
  __shared__ __align__(16) float Wl[128*40];
  __shared__ __align__(16) float xs[128*64];
  const int isbf = *flagp;
  const int t  = threadIdx.x;
  const int nb = blockIdx.x * 64;
  for (int idx = t; idx < 5120; idx += 256)
    Wl[idx] = ldf(W, idx, isbf);
  for (int idx = t; idx < 64*64; idx += 256){
    int nodeI = idx >> 6, cp = idx & 63;
    int g = nb + nodeI;
    float v0 = 0.f, v1 = 0.f;
    if (g < n){
      unsigned u = X2[(size_t)g*64 + cp];
      v0 = bflo(u); v1 = bfhi(u);
    }
    int c0 = 2*cp;
    xs[c0*64 + ((nodeI + c0) & 63)] = v0;
    xs[(c0+1)*64 + ((nodeI + c0 + 1) & 63)] = v1;
  }
  __syncthreads();
  const int jq = t & 3, ng = t >> 2;     // 4 ch-groups x 10ch, 1 node/thread
  const int j0 = jq * 10;
  const int g  = nb + ng;
  float acc[10] = {};
  const float2* W2p = (const float2*)Wl;
  for (int k = 0; k < 128; ++k){
    float xv = xs[k*64 + ((ng + k) & 63)];
    #pragma unroll
    for (int u = 0; u < 5; ++u){
      float2 wf = W2p[k*20 + jq*5 + u];
      acc[2*u]   += xv * wf.x;
      acc[2*u+1] += xv * wf.y;
    }
  }
  float ps = 0.f, pd = 0.f;
  #pragma unroll
  for (int u = 0; u < 10; ++u){
    float a = ldf(Wsrc, j0+u, isbf), d = ldf(Wdst, j0+u, isbf);
    ps += acc[u]*a; pd += acc[u]*d;
  }
  ps += __shfl_xor(ps,1); ps += __shfl_xor(ps,2);   // reduce across the 4 ch-groups
  pd += __shfl_xor(pd,1); pd += __shfl_xor(pd,2);
  if (g < n){
    #pragma unroll
    for (int u = 0; u < 5; ++u)
      H3[(size_t)g*20 + jq*5 + u] = pk(acc[2*u], acc[2*u+1]);
    if (jq == 0){ AL[g] = ps; AD[g] = pd; }
  }
}

// ---------------- aggregation (layers 1,2): wave/node, inline softmax denom ----
// H2 packed bf16 pairs; lane c holds channels 2c,2c+1 (same head: head = c>>4).
__global__ __launch_bounds__(256) void agg4(
    const unsigned* __restrict__ H2,
    const float* __restrict__ ALf, const float* __restrict__ ADf,
    const int* __restrict__ cnt, const int* __restrict__ start, const int* __restrict__ col,
    const void* __restrict__ bias, const void* __restrict__ bng, const void* __restrict__ bnb,
    const void* __restrict__ bnm,  const void* __restrict__ bnv,
    const int* __restrict__ flagp,
    unsigned* __restrict__ Hout, int n)
{
  const int isbf = *flagp;
  const int wave = threadIdx.x >> 6;
  const int lane = threadIdx.x & 63;
  const int node = blockIdx.x*4 + wave;
  if (node >= n) return;
  const int head = lane >> 4;
  const float ad = ADf[node*4 + head];
  const int base = start[node], deg = cnt[node];

  int s = col[base]; if ((unsigned)s >= (unsigned)n) s = 0;
  float asv = ALf[s*4 + head];
  unsigned hv = H2[(size_t)s*64 + lane];
  float accL = 0.f, accH = 0.f, l = 0.f;
  for (int i = 0; i < deg; ++i){
    int sn = s; float asn = asv; unsigned hn = hv;
    if (i + 1 < deg){
      sn = col[base + i + 1]; if ((unsigned)sn >= (unsigned)n) sn = 0;
      asn = ALf[sn*4 + head];
      hn  = H2[(size_t)sn*64 + lane];
    }
    float e = __expf(lrelu(asv + ad));
    l    += e;
    accL += e * bflo(hv);
    accH += e * bfhi(hv);
    s = sn; asv = asn; hv = hn;
  }
  const float rl = 1.f / l;
  const int c0 = 2*lane, c1 = c0 + 1;
  float v0 = fmaxf(accL*rl + ldf(bias,c0,isbf), 0.f);
  v0 = (v0 - ldf(bnm,c0,isbf)) * rsqrtf(ldf(bnv,c0,isbf) + BN_EPS) * ldf(bng,c0,isbf) + ldf(bnb,c0,isbf);
  float v1 = fmaxf(accH*rl + ldf(bias,c1,isbf), 0.f);
  v1 = (v1 - ldf(bnm,c1,isbf)) * rsqrtf(ldf(bnv,c1,isbf) + BN_EPS) * ldf(bng,c1,isbf) + ldf(bnb,c1,isbf);
  Hout[(size_t)node*64 + lane] = pk(v0, v1);
}

// ---------------- aggregation (layer 3) + log_softmax -------------------------
__global__ __launch_bounds__(256) void agg1(
    const unsigned* __restrict__ H3,
    const float* __restrict__ AL, const float* __restrict__ AD,
    const int* __restrict__ cnt, const int* __restrict__ start, const int* __restrict__ col,
    const void* __restrict__ b3, const int* __restrict__ flagp,
    void* __restrict__ out, int n)
{
  const int isbf = *flagp;
  const int wave = threadIdx.x >> 6;
  const int lane = threadIdx.x & 63;
  const int node = blockIdx.x*4 + wave;
  if (node >= n) return;
  const float ad = AD[node];
  const bool act = lane < 20;
  const int base = start[node], deg = cnt[node];

  int s = col[base]; if ((unsigned)s >= (unsigned)n) s = 0;
  float asv = AL[s];
  unsigned hv = act ? H3[(size_t)s*20 + lane] : 0u;
  float accL = 0.f, accH = 0.f, l = 0.f;
  for (int i = 0; i < deg; ++i){
    int sn = s; float asn = asv; unsigned hn = hv;
    if (i + 1 < deg){
      sn = col[base + i + 1]; if ((unsigned)sn >= (unsigned)n) sn = 0;
      asn = AL[sn];
      hn  = act ? H3[(size_t)sn*20 + lane] : 0u;
    }
    float e = __expf(lrelu(asv + ad));
    l    += e;
    accL += e * bflo(hv);
    accH += e * bfhi(hv);
    s = sn; asv = asn; hv = hn;
  }
  const float rl = 1.f / l;
  const int c0 = 2*lane;
  float z0 = act ? (accL*rl + ldf(b3, c0,     isbf)) : NEGBIG;
  float z1 = act ? (accH*rl + ldf(b3, c0 + 1, isbf)) : NEGBIG;
  float mx = fmaxf(z0, z1);
  #pragma unroll
  for (int off = 1; off < 64; off <<= 1) mx = fmaxf(mx, __shfl_xor(mx, off));
  float p = act ? (__expf(z0 - mx) + __expf(z1 - mx)) : 0.f;
  float sum = p;
  #pragma unroll
  for (int off = 1; off < 64; off <<= 1) sum += __shfl_xor(sum, off);
  if (act){
    float lg = __logf(sum);
    float r0 = z0 - mx - lg, r1 = z1 - mx - lg;
    if (isbf) ((unsigned*)out)[(size_t)node*20 + lane] = pk(r0, r1);
    else      ((float2*)out)[(size_t)node*20 + lane] = make_float2(r0, r1);
  }
}

// ---------------- launch ----------------
extern "C" void kernel_launch(void* const* d_in, const int* in_sizes, int n_in,
                              void* d_out, int out_size, void* d_ws, size_t ws_size,
                              hipStream_t stream)
{
  (void)n_in; (void)out_size; (void)ws_size;
  const void* x    = d_in[0];
  const int*  ei   = (const int*)d_in[1];
  const void* W1   = d_in[2];
  const void* as1  = d_in[3];
  const void* ad1  = d_in[4];
  const void* b1   = d_in[5];
  const void* W2   = d_in[6];
  const void* as2  = d_in[7];
  const void* ad2  = d_in[8];
  const void* b2   = d_in[9];
  const void* W3   = d_in[10];
  const void* as3  = d_in[11];
  const void* ad3  = d_in[12];
  const void* b3   = d_in[13];
  const void* bn1g = d_in[14];
  const void* bn1b = d_in[15];
  const void* bn1m = d_in[16];
  const void* bn1v = d_in[17];
  const void* bn2g = d_in[18];
  const void* bn2b = d_in[19];
  const void* bn2m = d_in[20];
  const void* bn2v = d_in[21];

  const int N  = in_sizes[0] / 128;
  const int E  = in_sizes[1] / 2;
  const int ET = E + N;

  char* w = (char*)d_ws;
  size_t off = 0;
  auto alloc = [&](size_t bytes)->char*{
    char* p = w + off; off = (off + bytes + 255) & ~(size_t)255; return p;
  };
  unsigned* H2A = (unsigned*)alloc((size_t)N*64*4);   // packed bf16 pairs
  unsigned* H2B = (unsigned*)alloc((size_t)N*64*4);
  unsigned* H3p = (unsigned*)alloc((size_t)N*20*4);
  float* AL   = (float*)alloc((size_t)N*4*4);
  float* AD   = (float*)alloc((size_t)N*4*4);
  int*   cnt    = (int*)alloc((size_t)N*4);
  int*   start  = (int*)alloc((size_t)N*4);
  int*   cursor = (int*)alloc((size_t)N*4);
  int*   col    = (int*)alloc((size_t)ET*4);
  int*   flag   = (int*)alloc(256);
  int*   total  = (int*)alloc(256);

  const int* srcp = ei;
  const int* dstp = ei + E;

  const int nb256 = (N + 255)/256, eb256 = (E + 255)/256;
  const int gb = (N + 63)/64, bb = (N + 3)/4;

  detect_dtype<<<1,256,0,stream>>>((const unsigned short*)W1, flag);

  csr_init <<<nb256,256,0,stream>>>(cnt, total, N);
  csr_count<<<eb256,256,0,stream>>>(dstp, cnt, E, N);
  csr_scan <<<nb256,256,0,stream>>>(cnt, start, total, N);
  csr_self <<<nb256,256,0,stream>>>(start, cursor, col, N);
  csr_fill <<<eb256,256,0,stream>>>(srcp, dstp, cursor, col, E, N);

  // layer 1
  gemm_al<<<gb,256,0,stream>>>(x, 0, W1, as1, ad1, flag, H2A, AL, AD, N);
  agg4<<<bb,256,0,stream>>>(H2A, AL, AD, cnt, start, col,
                            b1, bn1g, bn1b, bn1m, bn1v, flag, H2B, N);
  // layer 2
  gemm_al<<<gb,256,0,stream>>>(H2B, 1, W2, as2, ad2, flag, H2A, AL, AD, N);
  agg4<<<bb,256,0,stream>>>(H2A, AL, AD, cnt, start, col,
                            b2, bn2g, bn2b, bn2m, bn2v, flag, H2B, N);
  // layer 3
  gemm3<<<gb,256,0,stream>>>(H2B, W3, as3, ad3, flag, H3p, AL, AD, N);
  agg1<<<bb,256,0,stream>>>(H3p, AL, AD, cnt, start, col, b3, flag, d_out, N);
}

// Round 4
// 534.207 us; speedup vs baseline: 1.4591x; 1.2679x over previous
//
#include <hip/hip_runtime.h>
#include <hip/hip_bf16.h>
#include <math.h>

using bf16 = __hip_bfloat16;

#define LEAKY 0.2f
#define BN_EPS 1e-5f
#define NEGBIG -1e30f

__device__ __forceinline__ float lrelu(float z){ return z > 0.f ? z : LEAKY * z; }
__device__ __forceinline__ float bflo(unsigned u){ return __uint_as_float(u << 16); }
__device__ __forceinline__ float bfhi(unsigned u){ return __uint_as_float(u & 0xffff0000u); }
// pack two floats into bf16 pair (RNE)
__device__ __forceinline__ unsigned pk(float a, float b){
  unsigned ua = __float_as_uint(a), ub = __float_as_uint(b);
  ua += 0x7fffu + ((ua >> 16) & 1u);
  ub += 0x7fffu + ((ub >> 16) & 1u);
  return (ua >> 16) | (ub & 0xffff0000u);
}
// dtype-adaptive load: isbf=1 -> bf16, else fp32
__device__ __forceinline__ float ldf(const void* p, size_t i, int isbf){
  if (isbf) return (float)((const bf16*)p)[i];
  return ((const float*)p)[i];
}

// ---------------- input dtype detector (samples W1 bit patterns) ----------------
__global__ void detect_dtype(const unsigned short* __restrict__ w1bits, int* flag){
  __shared__ int cntr;
  if (threadIdx.x == 0) cntr = 0;
  __syncthreads();
  unsigned u = w1bits[threadIdx.x * 2];
  int e = (u >> 7) & 0xff;
  atomicAdd(&cntr, (e >= 64 && e <= 140) ? 1 : 0);
  __syncthreads();
  if (threadIdx.x == 0) *flag = (cntr >= 160) ? 1 : 0;
}

// ---------------- CSR build (dst-grouped, order-free segments; NO self loops) ---
__global__ void csr_init(int* cnt, int* total, int n){
  int g = blockIdx.x*256 + threadIdx.x;
  if (g < n) cnt[g] = 0;
  if (g == 0) *total = 0;
}
__global__ void csr_count(const int* __restrict__ dst, int* cnt, int e, int n){
  int g = blockIdx.x*256 + threadIdx.x;
  if (g < e){
    int d = dst[g];
    if ((unsigned)d < (unsigned)n) atomicAdd(&cnt[d], 1);
  }
}
__global__ void csr_scan(const int* __restrict__ cnt, int* start, int* cursor,
                         int* total, int n){
  __shared__ int s[256];
  __shared__ int base_s;
  int t = threadIdx.x;
  int g = blockIdx.x*256 + t;
  int v = (g < n) ? cnt[g] : 0;
  s[t] = v;
  __syncthreads();
  for (int off = 1; off < 256; off <<= 1){
    int x = (t >= off) ? s[t-off] : 0;
    __syncthreads();
    s[t] += x;
    __syncthreads();
  }
  if (t == 255) base_s = atomicAdd(total, s[255]);
  __syncthreads();
  if (g < n){ int st = base_s + s[t] - v; start[g] = st; cursor[g] = st; }
}
__global__ void csr_fill(const int* __restrict__ src, const int* __restrict__ dst,
                         int* cursor, int* col, int e, int n){
  int g = blockIdx.x*256 + threadIdx.x;
  if (g < e){
    int d = dst[g];
    if ((unsigned)d < (unsigned)n){
      int p = atomicAdd(&cursor[d], 1);
      col[p] = src[g];
    }
  }
}

// ---------------- GEMM 128x128 + fused al_src/al_dst (layers 1,2) ----------------
// block = 256 threads, 64 nodes/block; thread = 4 nodes x 8 channels.
// Output H2: packed bf16 pairs, [node][64] uints.
// xkind: 0 = external input (dtype per flag), 1 = internal packed bf16 pairs.
__global__ __launch_bounds__(256) void gemm_al(
    const void* __restrict__ X, int xkind,
    const void* __restrict__ W, const void* __restrict__ Wsrc, const void* __restrict__ Wdst,
    const int* __restrict__ flagp,
    unsigned* __restrict__ H2, float* __restrict__ AL, float* __restrict__ AD, int n)
{
  __shared__ __align__(16) float Wl[64*128];
  __shared__ __align__(16) float xs[128*64];
  const int isbf = *flagp;
  const int t  = threadIdx.x;
  const int nb = blockIdx.x * 64;
  const bool pairs = (xkind == 1) || isbf;  // bf16 raw rows == packed pair layout
  for (int idx = t; idx < 64*64; idx += 256){
    int nodeI = idx >> 6, cp = idx & 63;
    int g = nb + nodeI;
    float v0 = 0.f, v1 = 0.f;
    if (g < n){
      if (pairs){
        unsigned u = ((const unsigned*)X)[(size_t)g*64 + cp];
        v0 = bflo(u); v1 = bfhi(u);
      } else {
        float2 f = ((const float2*)X)[(size_t)g*64 + cp];
        v0 = f.x; v1 = f.y;
      }
    }
    int c0 = 2*cp;
    xs[c0*64 + ((nodeI + c0) & 63)] = v0;
    xs[(c0+1)*64 + ((nodeI + c0 + 1) & 63)] = v1;
  }
  const int jg = t & 15, ng = t >> 4;
  const int j0 = jg * 8;
  const int n4 = ng * 4;
  float acc[4][8];
  #pragma unroll
  for (int i = 0; i < 4; ++i)
    #pragma unroll
    for (int u = 0; u < 8; ++u) acc[i][u] = 0.f;

  for (int kc = 0; kc < 128; kc += 64){
    __syncthreads();
    for (int idx = t; idx < 64*128; idx += 256)
      Wl[idx] = ldf(W, (size_t)(kc + (idx >> 7))*128 + (idx & 127), isbf);
    __syncthreads();
    for (int kk = 0; kk < 64; ++kk){
      int k = kc + kk;
      float4 wa = *((const float4*)&Wl[kk*128 + j0]);
      float4 wb = *((const float4*)&Wl[kk*128 + j0 + 4]);
      float w[8] = {wa.x, wa.y, wa.z, wa.w, wb.x, wb.y, wb.z, wb.w};
      float xv[4];
      #pragma unroll
      for (int i = 0; i < 4; ++i) xv[i] = xs[k*64 + ((n4 + i + k) & 63)];
      #pragma unroll
      for (int i = 0; i < 4; ++i)
        #pragma unroll
        for (int u = 0; u < 8; ++u) acc[i][u] += xv[i] * w[u];
    }
  }

  float av[8], dv[8];
  #pragma unroll
  for (int u = 0; u < 8; ++u){ av[u] = ldf(Wsrc, j0+u, isbf); dv[u] = ldf(Wdst, j0+u, isbf); }
  const int head = jg >> 2;
  #pragma unroll
  for (int i = 0; i < 4; ++i){
    int g = nb + n4 + i;
    float ps = 0.f, pd = 0.f;
    #pragma unroll
    for (int u = 0; u < 8; ++u){ ps += acc[i][u]*av[u]; pd += acc[i][u]*dv[u]; }
    ps += __shfl_xor(ps, 1); ps += __shfl_xor(ps, 2);   // 4 lanes of one head
    pd += __shfl_xor(pd, 1); pd += __shfl_xor(pd, 2);
    if (g < n){
      uint4 hq;
      hq.x = pk(acc[i][0], acc[i][1]);
      hq.y = pk(acc[i][2], acc[i][3]);
      hq.z = pk(acc[i][4], acc[i][5]);
      hq.w = pk(acc[i][6], acc[i][7]);
      *((uint4*)&H2[(size_t)g*64 + jg*4]) = hq;
      if ((jg & 3) == 0){ AL[g*4 + head] = ps; AD[g*4 + head] = pd; }
    }
  }
}

// ---------------- GEMM 128x40 + fused al (layer 3, 1 head) ----------------
__global__ __launch_bounds__(256) void gemm3(
    const unsigned* __restrict__ X2, const void* __restrict__ W,
    const void* __restrict__ Wsrc, const void* __restrict__ Wdst,
    const int* __restrict__ flagp,
    unsigned* __restrict__ H3, float* __restrict__ AL, float* __restrict__ AD, int n)
{
  __shared__ __align__(16) float Wl[128*40];
  __shared__ __align__(16) float xs[128*64];
  const int isbf = *flagp;
  const int t  = threadIdx.x;
  const int nb = blockIdx.x * 64;
  for (int idx = t; idx < 5120; idx += 256)
    Wl[idx] = ldf(W, idx, isbf);
  for (int idx = t; idx < 64*64; idx += 256){
    int nodeI = idx >> 6, cp = idx & 63;
    int g = nb + nodeI;
    float v0 = 0.f, v1 = 0.f;
    if (g < n){
      unsigned u = X2[(size_t)g*64 + cp];
      v0 = bflo(u); v1 = bfhi(u);
    }
    int c0 = 2*cp;
    xs[c0*64 + ((nodeI + c0) & 63)] = v0;
    xs[(c0+1)*64 + ((nodeI + c0 + 1) & 63)] = v1;
  }
  __syncthreads();
  const int jq = t & 3, ng = t >> 2;     // 4 ch-groups x 10ch, 1 node/thread
  const int j0 = jq * 10;
  const int g  = nb + ng;
  float acc[10] = {};
  const float2* W2p = (const float2*)Wl;
  for (int k = 0; k < 128; ++k){
    float xv = xs[k*64 + ((ng + k) & 63)];
    #pragma unroll
    for (int u = 0; u < 5; ++u){
      float2 wf = W2p[k*20 + jq*5 + u];
      acc[2*u]   += xv * wf.x;
      acc[2*u+1] += xv * wf.y;
    }
  }
  float ps = 0.f, pd = 0.f;
  #pragma unroll
  for (int u = 0; u < 10; ++u){
    float a = ldf(Wsrc, j0+u, isbf), d = ldf(Wdst, j0+u, isbf);
    ps += acc[u]*a; pd += acc[u]*d;
  }
  ps += __shfl_xor(ps,1); ps += __shfl_xor(ps,2);   // reduce across the 4 ch-groups
  pd += __shfl_xor(pd,1); pd += __shfl_xor(pd,2);
  if (g < n){
    #pragma unroll
    for (int u = 0; u < 5; ++u)
      H3[(size_t)g*20 + jq*5 + u] = pk(acc[2*u], acc[2*u+1]);
    if (jq == 0){ AL[g] = ps; AD[g] = pd; }
  }
}

// ---------------- aggregation (layers 1,2): wave/node, 8-wide edge unroll ------
// H2 packed bf16 pairs; lane c holds channels 2c,2c+1 (head = c>>4).
// Self-loop handled analytically (uniform loads), not stored in CSR.
__global__ __launch_bounds__(256) void agg4(
    const unsigned* __restrict__ H2,
    const float* __restrict__ ALf, const float* __restrict__ ADf,
    const int* __restrict__ cnt, const int* __restrict__ start, const int* __restrict__ col,
    const void* __restrict__ bias, const void* __restrict__ bng, const void* __restrict__ bnb,
    const void* __restrict__ bnm,  const void* __restrict__ bnv,
    const int* __restrict__ flagp,
    unsigned* __restrict__ Hout, int n)
{
  const int isbf = *flagp;
  const int wave = threadIdx.x >> 6;
  const int lane = threadIdx.x & 63;
  const int node = blockIdx.x*4 + wave;
  if (node >= n) return;
  const int head = lane >> 4;
  const float ad = ADf[node*4 + head];
  const int base = start[node], deg = cnt[node];

  // self loop (uniform, coalesced)
  float accL, accH, l;
  {
    float e = __expf(lrelu(ALf[node*4 + head] + ad));
    unsigned h = H2[(size_t)node*64 + lane];
    l = e; accL = e * bflo(h); accH = e * bfhi(h);
  }

  int i = 0;
  for (; i + 8 <= deg; i += 8){
    int sv[8]; float av[8]; unsigned hv[8];
    #pragma unroll
    for (int u = 0; u < 8; ++u){
      int s = col[base + i + u];
      sv[u] = ((unsigned)s < (unsigned)n) ? s : 0;
    }
    #pragma unroll
    for (int u = 0; u < 8; ++u) av[u] = ALf[sv[u]*4 + head];
    #pragma unroll
    for (int u = 0; u < 8; ++u) hv[u] = H2[(size_t)sv[u]*64 + lane];
    #pragma unroll
    for (int u = 0; u < 8; ++u){
      float e = __expf(lrelu(av[u] + ad));
      l    += e;
      accL += e * bflo(hv[u]);
      accH += e * bfhi(hv[u]);
    }
  }
  for (; i < deg; ++i){
    int s = col[base + i];
    if ((unsigned)s >= (unsigned)n) s = 0;
    float a = ALf[s*4 + head];
    unsigned h = H2[(size_t)s*64 + lane];
    float e = __expf(lrelu(a + ad));
    l += e; accL += e * bflo(h); accH += e * bfhi(h);
  }

  const float rl = 1.f / l;
  const int c0 = 2*lane, c1 = c0 + 1;
  float v0 = fmaxf(accL*rl + ldf(bias,c0,isbf), 0.f);
  v0 = (v0 - ldf(bnm,c0,isbf)) * rsqrtf(ldf(bnv,c0,isbf) + BN_EPS) * ldf(bng,c0,isbf) + ldf(bnb,c0,isbf);
  float v1 = fmaxf(accH*rl + ldf(bias,c1,isbf), 0.f);
  v1 = (v1 - ldf(bnm,c1,isbf)) * rsqrtf(ldf(bnv,c1,isbf) + BN_EPS) * ldf(bng,c1,isbf) + ldf(bnb,c1,isbf);
  Hout[(size_t)node*64 + lane] = pk(v0, v1);
}

// ---------------- aggregation (layer 3) + log_softmax -------------------------
__global__ __launch_bounds__(256) void agg1(
    const unsigned* __restrict__ H3,
    const float* __restrict__ AL, const float* __restrict__ AD,
    const int* __restrict__ cnt, const int* __restrict__ start, const int* __restrict__ col,
    const void* __restrict__ b3, const int* __restrict__ flagp,
    void* __restrict__ out, int n)
{
  const int isbf = *flagp;
  const int wave = threadIdx.x >> 6;
  const int lane = threadIdx.x & 63;
  const int node = blockIdx.x*4 + wave;
  if (node >= n) return;
  const float ad = AD[node];
  const bool act = lane < 20;
  const int base = start[node], deg = cnt[node];

  // self loop
  float accL, accH, l;
  {
    float e = __expf(lrelu(AL[node] + ad));
    unsigned h = act ? H3[(size_t)node*20 + lane] : 0u;
    l = e; accL = e * bflo(h); accH = e * bfhi(h);
  }

  int i = 0;
  for (; i + 8 <= deg; i += 8){
    int sv[8]; float av[8]; unsigned hv[8];
    #pragma unroll
    for (int u = 0; u < 8; ++u){
      int s = col[base + i + u];
      sv[u] = ((unsigned)s < (unsigned)n) ? s : 0;
    }
    #pragma unroll
    for (int u = 0; u < 8; ++u) av[u] = AL[sv[u]];
    #pragma unroll
    for (int u = 0; u < 8; ++u) hv[u] = act ? H3[(size_t)sv[u]*20 + lane] : 0u;
    #pragma unroll
    for (int u = 0; u < 8; ++u){
      float e = __expf(lrelu(av[u] + ad));
      l    += e;
      accL += e * bflo(hv[u]);
      accH += e * bfhi(hv[u]);
    }
  }
  for (; i < deg; ++i){
    int s = col[base + i];
    if ((unsigned)s >= (unsigned)n) s = 0;
    float a = AL[s];
    unsigned h = act ? H3[(size_t)s*20 + lane] : 0u;
    float e = __expf(lrelu(a + ad));
    l += e; accL += e * bflo(h); accH += e * bfhi(h);
  }

  const float rl = 1.f / l;
  const int c0 = 2*lane;
  float z0 = act ? (accL*rl + ldf(b3, c0,     isbf)) : NEGBIG;
  float z1 = act ? (accH*rl + ldf(b3, c0 + 1, isbf)) : NEGBIG;
  float mx = fmaxf(z0, z1);
  #pragma unroll
  for (int off = 1; off < 64; off <<= 1) mx = fmaxf(mx, __shfl_xor(mx, off));
  float p = act ? (__expf(z0 - mx) + __expf(z1 - mx)) : 0.f;
  float sum = p;
  #pragma unroll
  for (int off = 1; off < 64; off <<= 1) sum += __shfl_xor(sum, off);
  if (act){
    float lg = __logf(sum);
    float r0 = z0 - mx - lg, r1 = z1 - mx - lg;
    if (isbf) ((unsigned*)out)[(size_t)node*20 + lane] = pk(r0, r1);
    else      ((float2*)out)[(size_t)node*20 + lane] = make_float2(r0, r1);
  }
}

// ---------------- launch ----------------
extern "C" void kernel_launch(void* const* d_in, const int* in_sizes, int n_in,
                              void* d_out, int out_size, void* d_ws, size_t ws_size,
                              hipStream_t stream)
{
  (void)n_in; (void)out_size; (void)ws_size;
  const void* x    = d_in[0];
  const int*  ei   = (const int*)d_in[1];
  const void* W1   = d_in[2];
  const void* as1  = d_in[3];
  const void* ad1  = d_in[4];
  const void* b1   = d_in[5];
  const void* W2   = d_in[6];
  const void* as2  = d_in[7];
  const void* ad2  = d_in[8];
  const void* b2   = d_in[9];
  const void* W3   = d_in[10];
  const void* as3  = d_in[11];
  const void* ad3  = d_in[12];
  const void* b3   = d_in[13];
  const void* bn1g = d_in[14];
  const void* bn1b = d_in[15];
  const void* bn1m = d_in[16];
  const void* bn1v = d_in[17];
  const void* bn2g = d_in[18];
  const void* bn2b = d_in[19];
  const void* bn2m = d_in[20];
  const void* bn2v = d_in[21];

  const int N  = in_sizes[0] / 128;
  const int E  = in_sizes[1] / 2;

  char* w = (char*)d_ws;
  size_t off = 0;
  auto alloc = [&](size_t bytes)->char*{
    char* p = w + off; off = (off + bytes + 255) & ~(size_t)255; return p;
  };
  unsigned* H2A = (unsigned*)alloc((size_t)N*64*4);   // packed bf16 pairs
  unsigned* H2B = (unsigned*)alloc((size_t)N*64*4);
  unsigned* H3p = (unsigned*)alloc((size_t)N*20*4);
  float* AL   = (float*)alloc((size_t)N*4*4);
  float* AD   = (float*)alloc((size_t)N*4*4);
  int*   cnt    = (int*)alloc((size_t)N*4);
  int*   start  = (int*)alloc((size_t)N*4);
  int*   cursor = (int*)alloc((size_t)N*4);
  int*   col    = (int*)alloc((size_t)E*4);
  int*   flag   = (int*)alloc(256);
  int*   total  = (int*)alloc(256);

  const int* srcp = ei;
  const int* dstp = ei + E;

  const int nb256 = (N + 255)/256, eb256 = (E + 255)/256;
  const int gb = (N + 63)/64, bb = (N + 3)/4;

  detect_dtype<<<1,256,0,stream>>>((const unsigned short*)W1, flag);

  csr_init <<<nb256,256,0,stream>>>(cnt, total, N);
  csr_count<<<eb256,256,0,stream>>>(dstp, cnt, E, N);
  csr_scan <<<nb256,256,0,stream>>>(cnt, start, cursor, total, N);
  csr_fill <<<eb256,256,0,stream>>>(srcp, dstp, cursor, col, E, N);

  // layer 1
  gemm_al<<<gb,256,0,stream>>>(x, 0, W1, as1, ad1, flag, H2A, AL, AD, N);
  agg4<<<bb,256,0,stream>>>(H2A, AL, AD, cnt, start, col,
                            b1, bn1g, bn1b, bn1m, bn1v, flag, H2B, N);
  // layer 2
  gemm_al<<<gb,256,0,stream>>>(H2B, 1, W2, as2, ad2, flag, H2A, AL, AD, N);
  agg4<<<bb,256,0,stream>>>(H2A, AL, AD, cnt, start, col,
                            b2, bn2g, bn2b, bn2m, bn2v, flag, H2B, N);
  // layer 3
  gemm3<<<gb,256,0,stream>>>(H2B, W3, as3, ad3, flag, H3p, AL, AD, N);
  agg1<<<bb,256,0,stream>>>(H3p, AL, AD, cnt, start, col, b3, flag, d_out, N);
}

// Round 5
// 413.801 us; speedup vs baseline: 1.8837x; 1.2910x over previous
//
#include <hip/hip_runtime.h>
#include <hip/hip_bf16.h>
#include <math.h>

using bf16 = __hip_bfloat16;
using frag8 = __attribute__((ext_vector_type(8))) short;
using f32x4 = __attribute__((ext_vector_type(4))) float;

#define LEAKY 0.2f
#define BN_EPS 1e-5f
#define NEGBIG -1e30f

__device__ __forceinline__ float lrelu(float z){ return z > 0.f ? z : LEAKY * z; }
__device__ __forceinline__ float bflo(unsigned u){ return __uint_as_float(u << 16); }
__device__ __forceinline__ float bfhi(unsigned u){ return __uint_as_float(u & 0xffff0000u); }
// pack two floats into bf16 pair (RNE)
__device__ __forceinline__ unsigned pk(float a, float b){
  unsigned ua = __float_as_uint(a), ub = __float_as_uint(b);
  ua += 0x7fffu + ((ua >> 16) & 1u);
  ub += 0x7fffu + ((ub >> 16) & 1u);
  return (ua >> 16) | (ub & 0xffff0000u);
}
// dtype-adaptive load: isbf=1 -> bf16, else fp32
__device__ __forceinline__ float ldf(const void* p, size_t i, int isbf){
  if (isbf) return (float)((const bf16*)p)[i];
  return ((const float*)p)[i];
}

union U4F8 { uint4 u; frag8 f; };

// A-frag loaders: lane m=lane&15 -> node, k0 = s*32 + quad*8, 8 bf16 = 16B
__device__ __forceinline__ frag8 load_a_pairs(const unsigned* __restrict__ X2, int node, int k0){
  U4F8 v; v.u = *((const uint4*)(X2 + (size_t)node*64 + (k0 >> 1))); return v.f;
}
__device__ __forceinline__ frag8 load_a_f32(const float* __restrict__ X, int node, int k0){
  float4 q0 = *((const float4*)(X + (size_t)node*128 + k0));
  float4 q1 = *((const float4*)(X + (size_t)node*128 + k0 + 4));
  U4F8 v; v.u = make_uint4(pk(q0.x,q0.y), pk(q0.z,q0.w), pk(q1.x,q1.y), pk(q1.z,q1.w));
  return v.f;
}

// ---------------- input dtype detector (samples W1 bit patterns) ----------------
__global__ void detect_dtype(const unsigned short* __restrict__ w1bits, int* flag){
  __shared__ int cntr;
  if (threadIdx.x == 0) cntr = 0;
  __syncthreads();
  unsigned u = w1bits[threadIdx.x * 2];
  int e = (u >> 7) & 0xff;
  atomicAdd(&cntr, (e >= 64 && e <= 140) ? 1 : 0);
  __syncthreads();
  if (threadIdx.x == 0) *flag = (cntr >= 160) ? 1 : 0;
}

// ---------------- CSR build (dst-grouped, order-free segments; NO self loops) ---
__global__ void csr_init(int* cnt, int* total, int n){
  int g = blockIdx.x*256 + threadIdx.x;
  if (g < n) cnt[g] = 0;
  if (g == 0) *total = 0;
}
__global__ void csr_count(const int* __restrict__ dst, int* cnt, int e, int n){
  int g = blockIdx.x*256 + threadIdx.x;
  if (g < e){
    int d = dst[g];
    if ((unsigned)d < (unsigned)n) atomicAdd(&cnt[d], 1);
  }
}
__global__ void csr_scan(const int* __restrict__ cnt, int* start, int* cursor,
                         int* total, int n){
  __shared__ int s[256];
  __shared__ int base_s;
  int t = threadIdx.x;
  int g = blockIdx.x*256 + t;
  int v = (g < n) ? cnt[g] : 0;
  s[t] = v;
  __syncthreads();
  for (int off = 1; off < 256; off <<= 1){
    int x = (t >= off) ? s[t-off] : 0;
    __syncthreads();
    s[t] += x;
    __syncthreads();
  }
  if (t == 255) base_s = atomicAdd(total, s[255]);
  __syncthreads();
  if (g < n){ int st = base_s + s[t] - v; start[g] = st; cursor[g] = st; }
}
__global__ void csr_fill(const int* __restrict__ src, const int* __restrict__ dst,
                         int* cursor, int* col, int e, int n){
  int g = blockIdx.x*256 + threadIdx.x;
  if (g < e){
    int d = dst[g];
    if ((unsigned)d < (unsigned)n){
      int p = atomicAdd(&cursor[d], 1);
      col[p] = src[g];
    }
  }
}

// ---------------- MFMA GEMM 128x128 + fused al (layers 1,2) --------------------
// block = 256 (4 waves). wave w = head w = out cols [32w, 32w+32).
// B-frags (W^T) hoisted to registers; A-frags straight from global; grid-stride
// over 16-node tiles. Output H2 packed bf16 pairs.
__global__ __launch_bounds__(256) void gemm_al_mfma(
    const void* __restrict__ X, int xkind,   // 0 = external input, 1 = packed pairs
    const void* __restrict__ W, const void* __restrict__ Wsrc, const void* __restrict__ Wdst,
    const int* __restrict__ flagp,
    unsigned* __restrict__ H2, float* __restrict__ AL, float* __restrict__ AD,
    int n, int ntiles)
{
  __shared__ unsigned short WT[128*136];   // W^T bf16, stride 136 (bank-stagger)
  const int isbf = *flagp;
  const int t = threadIdx.x;
  if (isbf){
    const unsigned short* W16 = (const unsigned short*)W;
    for (int idx = t; idx < 16384; idx += 256){
      int k = idx >> 7, nn = idx & 127;
      WT[nn*136 + k] = W16[idx];
    }
  } else {
    const float* Wf = (const float*)W;
    for (int idx = t; idx < 16384; idx += 256){
      int k = idx >> 7, nn = idx & 127;
      WT[nn*136 + k] = (unsigned short)(pk(Wf[idx], 0.f) & 0xffffu);
    }
  }
  __syncthreads();
  const int w = t >> 6;          // wave == head
  const int lane = t & 63;
  const int m = lane & 15, quad = lane >> 4;

  // B frags: bf[s][ct]: B[k][n], n = 32w+16ct+m, k = 32s+8quad+j
  frag8 bf[4][2];
  #pragma unroll
  for (int s = 0; s < 4; ++s)
    #pragma unroll
    for (int ct = 0; ct < 2; ++ct){
      int colc = w*32 + ct*16 + m;
      int k0 = s*32 + quad*8;
      U4F8 v; v.u = *((const uint4*)&WT[colc*136 + k0]);
      bf[s][ct] = v.f;
    }
  float avv[2], dvv[2];
  #pragma unroll
  for (int ct = 0; ct < 2; ++ct){
    int colc = w*32 + ct*16 + m;
    avv[ct] = ldf(Wsrc, colc, isbf);
    dvv[ct] = ldf(Wdst, colc, isbf);
  }
  const bool pairs = (xkind == 1) || isbf;  // bf16 rows == packed-pair layout

  for (int tile = blockIdx.x; tile < ntiles; tile += gridDim.x){
    const int mb = tile*16;
    int nodeA = mb + m; if (nodeA >= n) nodeA = n - 1;
    frag8 af[4];
    #pragma unroll
    for (int s = 0; s < 4; ++s){
      int k0 = s*32 + quad*8;
      af[s] = pairs ? load_a_pairs((const unsigned*)X, nodeA, k0)
                    : load_a_f32((const float*)X, nodeA, k0);
    }
    f32x4 acc0 = {0.f,0.f,0.f,0.f}, acc1 = {0.f,0.f,0.f,0.f};
    #pragma unroll
    for (int s = 0; s < 4; ++s){
      acc0 = __builtin_amdgcn_mfma_f32_16x16x32_bf16(af[s], bf[s][0], acc0, 0,0,0);
      acc1 = __builtin_amdgcn_mfma_f32_16x16x32_bf16(af[s], bf[s][1], acc1, 0,0,0);
    }
    // epilogue: D col = m (within tile), row(node) = quad*4 + r
    #pragma unroll
    for (int r = 0; r < 4; ++r){
      int g = mb + quad*4 + r;
      float v0 = acc0[r], v1 = acc1[r];
      unsigned u0 = pk(v0, __shfl_xor(v0, 1));
      unsigned u1 = pk(v1, __shfl_xor(v1, 1));
      bool ok = g < n;
      if (((lane & 1) == 0) && ok){
        H2[(size_t)g*64 + w*16 + (m >> 1)]     = u0;
        H2[(size_t)g*64 + w*16 + 8 + (m >> 1)] = u1;
      }
      float s1 = v0*avv[0] + v1*avv[1];
      float s2 = v0*dvv[0] + v1*dvv[1];
      s1 += __shfl_xor(s1,1); s1 += __shfl_xor(s1,2); s1 += __shfl_xor(s1,4); s1 += __shfl_xor(s1,8);
      s2 += __shfl_xor(s2,1); s2 += __shfl_xor(s2,2); s2 += __shfl_xor(s2,4); s2 += __shfl_xor(s2,8);
      if (m == 0 && ok){ AL[g*4 + w] = s1; AD[g*4 + w] = s2; }
    }
  }
}

// ---------------- MFMA GEMM 128x40 + fused al (layer 3) -----------------------
// 40 cols -> 3 col-tiles (zero-padded to 48). wave w handles node tile tg*4+w.
__global__ __launch_bounds__(256) void gemm3_mfma(
    const unsigned* __restrict__ X2, const void* __restrict__ W,
    const void* __restrict__ Wsrc, const void* __restrict__ Wdst,
    const int* __restrict__ flagp,
    unsigned* __restrict__ H3, float* __restrict__ AL, float* __restrict__ AD,
    int n, int ntiles)
{
  __shared__ unsigned short WT[48*136];
  const int isbf = *flagp;
  const int t = threadIdx.x;
  for (int idx = t; idx < 128*64; idx += 256){
    int c = idx & 63, k = idx >> 6;
    if (c < 48){
      unsigned short v = 0;
      if (c < 40){
        if (isbf) v = ((const unsigned short*)W)[k*40 + c];
        else      v = (unsigned short)(pk(((const float*)W)[k*40 + c], 0.f) & 0xffffu);
      }
      WT[c*136 + k] = v;
    }
  }
  __syncthreads();
  const int w = t >> 6;
  const int lane = t & 63;
  const int m = lane & 15, quad = lane >> 4;

  frag8 bf[4][3];
  float avv[3], dvv[3];
  #pragma unroll
  for (int ct = 0; ct < 3; ++ct){
    int colc = ct*16 + m;
    #pragma unroll
    for (int s = 0; s < 4; ++s){
      int k0 = s*32 + quad*8;
      U4F8 v; v.u = *((const uint4*)&WT[colc*136 + k0]);
      bf[s][ct] = v.f;
    }
    avv[ct] = (colc < 40) ? ldf(Wsrc, colc, isbf) : 0.f;
    dvv[ct] = (colc < 40) ? ldf(Wdst, colc, isbf) : 0.f;
  }

  for (int tg = blockIdx.x; tg*4 < ntiles; tg += gridDim.x){
    const int tile = tg*4 + w;
    if (tile >= ntiles) continue;
    const int mb = tile*16;
    int nodeA = mb + m; if (nodeA >= n) nodeA = n - 1;
    frag8 af[4];
    #pragma unroll
    for (int s = 0; s < 4; ++s)
      af[s] = load_a_pairs(X2, nodeA, s*32 + quad*8);
    f32x4 acc[3];
    #pragma unroll
    for (int ct = 0; ct < 3; ++ct) acc[ct] = (f32x4){0.f,0.f,0.f,0.f};
    #pragma unroll
    for (int s = 0; s < 4; ++s){
      acc[0] = __builtin_amdgcn_mfma_f32_16x16x32_bf16(af[s], bf[s][0], acc[0], 0,0,0);
      acc[1] = __builtin_amdgcn_mfma_f32_16x16x32_bf16(af[s], bf[s][1], acc[1], 0,0,0);
      acc[2] = __builtin_amdgcn_mfma_f32_16x16x32_bf16(af[s], bf[s][2], acc[2], 0,0,0);
    }
    #pragma unroll
    for (int r = 0; r < 4; ++r){
      int g = mb + quad*4 + r;
      bool ok = g < n;
      float ps = 0.f, pd = 0.f;
      #pragma unroll
      for (int ct = 0; ct < 3; ++ct){
        float v = acc[ct][r];
        ps += v*avv[ct]; pd += v*dvv[ct];
        unsigned u = pk(v, __shfl_xor(v, 1));
        bool stok = ((lane & 1) == 0) && ok && (ct < 2 || m < 8);
        if (stok) H3[(size_t)g*20 + ct*8 + (m >> 1)] = u;
      }
      ps += __shfl_xor(ps,1); ps += __shfl_xor(ps,2); ps += __shfl_xor(ps,4); ps += __shfl_xor(ps,8);
      pd += __shfl_xor(pd,1); pd += __shfl_xor(pd,2); pd += __shfl_xor(pd,4); pd += __shfl_xor(pd,8);
      if (m == 0 && ok){ AL[g] = ps; AD[g] = pd; }
    }
  }
}

// ---------------- aggregation (layers 1,2): wave/node, 8-wide edge unroll ------
__global__ __launch_bounds__(256) void agg4(
    const unsigned* __restrict__ H2,
    const float* __restrict__ ALf, const float* __restrict__ ADf,
    const int* __restrict__ cnt, const int* __restrict__ start, const int* __restrict__ col,
    const void* __restrict__ bias, const void* __restrict__ bng, const void* __restrict__ bnb,
    const void* __restrict__ bnm,  const void* __restrict__ bnv,
    const int* __restrict__ flagp,
    unsigned* __restrict__ Hout, int n)
{
  const int isbf = *flagp;
  const int wave = threadIdx.x >> 6;
  const int lane = threadIdx.x & 63;
  const int node = blockIdx.x*4 + wave;
  if (node >= n) return;
  const int head = lane >> 4;
  const float ad = ADf[node*4 + head];
  const int base = start[node], deg = cnt[node];

  float accL, accH, l;
  {
    float e = __expf(lrelu(ALf[node*4 + head] + ad));
    unsigned h = H2[(size_t)node*64 + lane];
    l = e; accL = e * bflo(h); accH = e * bfhi(h);
  }

  int i = 0;
  for (; i + 8 <= deg; i += 8){
    int sv[8]; float av[8]; unsigned hv[8];
    #pragma unroll
    for (int u = 0; u < 8; ++u){
      int s = col[base + i + u];
      sv[u] = ((unsigned)s < (unsigned)n) ? s : 0;
    }
    #pragma unroll
    for (int u = 0; u < 8; ++u) av[u] = ALf[sv[u]*4 + head];
    #pragma unroll
    for (int u = 0; u < 8; ++u) hv[u] = H2[(size_t)sv[u]*64 + lane];
    #pragma unroll
    for (int u = 0; u < 8; ++u){
      float e = __expf(lrelu(av[u] + ad));
      l    += e;
      accL += e * bflo(hv[u]);
      accH += e * bfhi(hv[u]);
    }
  }
  for (; i < deg; ++i){
    int s = col[base + i];
    if ((unsigned)s >= (unsigned)n) s = 0;
    float a = ALf[s*4 + head];
    unsigned h = H2[(size_t)s*64 + lane];
    float e = __expf(lrelu(a + ad));
    l += e; accL += e * bflo(h); accH += e * bfhi(h);
  }

  const float rl = 1.f / l;
  const int c0 = 2*lane, c1 = c0 + 1;
  float v0 = fmaxf(accL*rl + ldf(bias,c0,isbf), 0.f);
  v0 = (v0 - ldf(bnm,c0,isbf)) * rsqrtf(ldf(bnv,c0,isbf) + BN_EPS) * ldf(bng,c0,isbf) + ldf(bnb,c0,isbf);
  float v1 = fmaxf(accH*rl + ldf(bias,c1,isbf), 0.f);
  v1 = (v1 - ldf(bnm,c1,isbf)) * rsqrtf(ldf(bnv,c1,isbf) + BN_EPS) * ldf(bng,c1,isbf) + ldf(bnb,c1,isbf);
  Hout[(size_t)node*64 + lane] = pk(v0, v1);
}

// ---------------- aggregation (layer 3) + log_softmax -------------------------
__global__ __launch_bounds__(256) void agg1(
    const unsigned* __restrict__ H3,
    const float* __restrict__ AL, const float* __restrict__ AD,
    const int* __restrict__ cnt, const int* __restrict__ start, const int* __restrict__ col,
    const void* __restrict__ b3, const int* __restrict__ flagp,
    void* __restrict__ out, int n)
{
  const int isbf = *flagp;
  const int wave = threadIdx.x >> 6;
  const int lane = threadIdx.x & 63;
  const int node = blockIdx.x*4 + wave;
  if (node >= n) return;
  const float ad = AD[node];
  const bool act = lane < 20;
  const int base = start[node], deg = cnt[node];

  float accL, accH, l;
  {
    float e = __expf(lrelu(AL[node] + ad));
    unsigned h = act ? H3[(size_t)node*20 + lane] : 0u;
    l = e; accL = e * bflo(h); accH = e * bfhi(h);
  }

  int i = 0;
  for (; i + 8 <= deg; i += 8){
    int sv[8]; float av[8]; unsigned hv[8];
    #pragma unroll
    for (int u = 0; u < 8; ++u){
      int s = col[base + i + u];
      sv[u] = ((unsigned)s < (unsigned)n) ? s : 0;
    }
    #pragma unroll
    for (int u = 0; u < 8; ++u) av[u] = AL[sv[u]];
    #pragma unroll
    for (int u = 0; u < 8; ++u) hv[u] = act ? H3[(size_t)sv[u]*20 + lane] : 0u;
    #pragma unroll
    for (int u = 0; u < 8; ++u){
      float e = __expf(lrelu(av[u] + ad));
      l    += e;
      accL += e * bflo(hv[u]);
      accH += e * bfhi(hv[u]);
    }
  }
  for (; i < deg; ++i){
    int s = col[base + i];
    if ((unsigned)s >= (unsigned)n) s = 0;
    float a = AL[s];
    unsigned h = act ? H3[(size_t)s*20 + lane] : 0u;
    float e = __expf(lrelu(a + ad));
    l += e; accL += e * bflo(h); accH += e * bfhi(h);
  }

  const float rl = 1.f / l;
  const int c0 = 2*lane;
  float z0 = act ? (accL*rl + ldf(b3, c0,     isbf)) : NEGBIG;
  float z1 = act ? (accH*rl + ldf(b3, c0 + 1, isbf)) : NEGBIG;
  float mx = fmaxf(z0, z1);
  #pragma unroll
  for (int off = 1; off < 64; off <<= 1) mx = fmaxf(mx, __shfl_xor(mx, off));
  float p = act ? (__expf(z0 - mx) + __expf(z1 - mx)) : 0.f;
  float sum = p;
  #pragma unroll
  for (int off = 1; off < 64; off <<= 1) sum += __shfl_xor(sum, off);
  if (act){
    float lg = __logf(sum);
    float r0 = z0 - mx - lg, r1 = z1 - mx - lg;
    if (isbf) ((unsigned*)out)[(size_t)node*20 + lane] = pk(r0, r1);
    else      ((float2*)out)[(size_t)node*20 + lane] = make_float2(r0, r1);
  }
}

// ---------------- launch ----------------
extern "C" void kernel_launch(void* const* d_in, const int* in_sizes, int n_in,
                              void* d_out, int out_size, void* d_ws, size_t ws_size,
                              hipStream_t stream)
{
  (void)n_in; (void)out_size; (void)ws_size;
  const void* x    = d_in[0];
  const int*  ei   = (const int*)d_in[1];
  const void* W1   = d_in[2];
  const void* as1  = d_in[3];
  const void* ad1  = d_in[4];
  const void* b1   = d_in[5];
  const void* W2   = d_in[6];
  const void* as2  = d_in[7];
  const void* ad2  = d_in[8];
  const void* b2   = d_in[9];
  const void* W3   = d_in[10];
  const void* as3  = d_in[11];
  const void* ad3  = d_in[12];
  const void* b3   = d_in[13];
  const void* bn1g = d_in[14];
  const void* bn1b = d_in[15];
  const void* bn1m = d_in[16];
  const void* bn1v = d_in[17];
  const void* bn2g = d_in[18];
  const void* bn2b = d_in[19];
  const void* bn2m = d_in[20];
  const void* bn2v = d_in[21];

  const int N  = in_sizes[0] / 128;
  const int E  = in_sizes[1] / 2;
  const int ntiles = (N + 15) / 16;

  char* w = (char*)d_ws;
  size_t off = 0;
  auto alloc = [&](size_t bytes)->char*{
    char* p = w + off; off = (off + bytes + 255) & ~(size_t)255; return p;
  };
  unsigned* H2A = (unsigned*)alloc((size_t)N*64*4);   // packed bf16 pairs
  unsigned* H2B = (unsigned*)alloc((size_t)N*64*4);
  unsigned* H3p = (unsigned*)alloc((size_t)N*20*4);
  float* AL   = (float*)alloc((size_t)N*4*4);
  float* AD   = (float*)alloc((size_t)N*4*4);
  int*   cnt    = (int*)alloc((size_t)N*4);
  int*   start  = (int*)alloc((size_t)N*4);
  int*   cursor = (int*)alloc((size_t)N*4);
  int*   col    = (int*)alloc((size_t)E*4);
  int*   flag   = (int*)alloc(256);
  int*   total  = (int*)alloc(256);

  const int* srcp = ei;
  const int* dstp = ei + E;

  const int nb256 = (N + 255)/256, eb256 = (E + 255)/256;
  const int bb = (N + 3)/4;
  int g1 = ntiles < 625 ? ntiles : 625;
  int g3 = (ntiles + 3)/4; if (g3 > 400) g3 = 400;

  detect_dtype<<<1,256,0,stream>>>((const unsigned short*)W1, flag);

  csr_init <<<nb256,256,0,stream>>>(cnt, total, N);
  csr_count<<<eb256,256,0,stream>>>(dstp, cnt, E, N);
  csr_scan <<<nb256,256,0,stream>>>(cnt, start, cursor, total, N);
  csr_fill <<<eb256,256,0,stream>>>(srcp, dstp, cursor, col, E, N);

  // layer 1
  gemm_al_mfma<<<g1,256,0,stream>>>(x, 0, W1, as1, ad1, flag, H2A, AL, AD, N, ntiles);
  agg4<<<bb,256,0,stream>>>(H2A, AL, AD, cnt, start, col,
                            b1, bn1g, bn1b, bn1m, bn1v, flag, H2B, N);
  // layer 2
  gemm_al_mfma<<<g1,256,0,stream>>>(H2B, 1, W2, as2, ad2, flag, H2A, AL, AD, N, ntiles);
  agg4<<<bb,256,0,stream>>>(H2A, AL, AD, cnt, start, col,
                            b2, bn2g, bn2b, bn2m, bn2v, flag, H2B, N);
  // layer 3
  gemm3_mfma<<<g3,256,0,stream>>>(H2B, W3, as3, ad3, flag, H3p, AL, AD, N, ntiles);
  agg1<<<bb,256,0,stream>>>(H3p, AL, AD, cnt, start, col, b3, flag, d_out, N);
}

// Round 6
// 381.703 us; speedup vs baseline: 2.0421x; 1.0841x over previous
//
#include <hip/hip_runtime.h>
#include <hip/hip_bf16.h>
#include <math.h>

using bf16 = __hip_bfloat16;
using frag8 = __attribute__((ext_vector_type(8))) short;
using f32x4 = __attribute__((ext_vector_type(4))) float;

#define LEAKY 0.2f
#define BN_EPS 1e-5f
#define NEGBIG -1e30f

__device__ __forceinline__ float lrelu(float z){ return z > 0.f ? z : LEAKY * z; }
__device__ __forceinline__ float bflo(unsigned u){ return __uint_as_float(u << 16); }
__device__ __forceinline__ float bfhi(unsigned u){ return __uint_as_float(u & 0xffff0000u); }
// pack two floats into bf16 pair (RNE)
__device__ __forceinline__ unsigned pk(float a, float b){
  unsigned ua = __float_as_uint(a), ub = __float_as_uint(b);
  ua += 0x7fffu + ((ua >> 16) & 1u);
  ub += 0x7fffu + ((ub >> 16) & 1u);
  return (ua >> 16) | (ub & 0xffff0000u);
}
// dtype-adaptive load: isbf=1 -> bf16, else fp32
__device__ __forceinline__ float ldf(const void* p, size_t i, int isbf){
  if (isbf) return (float)((const bf16*)p)[i];
  return ((const float*)p)[i];
}

union U4F8 { uint4 u; frag8 f; };

// A-frag loaders: lane m=lane&15 -> node, k0 = s*32 + quad*8, 8 bf16 = 16B
__device__ __forceinline__ frag8 load_a_pairs(const unsigned* __restrict__ X2, int node, int k0){
  U4F8 v; v.u = *((const uint4*)(X2 + (size_t)node*64 + (k0 >> 1))); return v.f;
}
__device__ __forceinline__ frag8 load_a_f32(const float* __restrict__ X, int node, int k0){
  float4 q0 = *((const float4*)(X + (size_t)node*128 + k0));
  float4 q1 = *((const float4*)(X + (size_t)node*128 + k0 + 4));
  U4F8 v; v.u = make_uint4(pk(q0.x,q0.y), pk(q0.z,q0.w), pk(q1.x,q1.y), pk(q1.z,q1.w));
  return v.f;
}

// ------------- head init (-1) + fused input-dtype detector (block 0) ----------
__global__ void init_detect(int* head, const unsigned short* __restrict__ w1bits,
                            int* flag, int n){
  int g = blockIdx.x*256 + threadIdx.x;
  if (g < n) head[g] = -1;
  if (blockIdx.x == 0){
    __shared__ int cntr;
    if (threadIdx.x == 0) cntr = 0;
    __syncthreads();
    unsigned u = w1bits[threadIdx.x * 2];
    int e = (u >> 7) & 0xff;
    atomicAdd(&cntr, (e >= 64 && e <= 140) ? 1 : 0);
    __syncthreads();
    if (threadIdx.x == 0) *flag = (cntr >= 160) ? 1 : 0;
  }
}

// ------------- chain build: next[e] = atomicExch(&head[dst[e]], e) ------------
// next writes coalesced; head atomics hot in L2 (no scattered line writebacks).
__global__ void chain_build(const int* __restrict__ dst, int* head, int* next,
                            int e, int n){
  int g = blockIdx.x*256 + threadIdx.x;
  if (g < e){
    int d = dst[g];
    next[g] = ((unsigned)d < (unsigned)n) ? atomicExch(&head[d], g) : -1;
  }
}

// ------------- per-node chain walk: degree count ------------------------------
__global__ void chain_count(const int* __restrict__ head, const int* __restrict__ next,
                            int* cnt, int* total, int n){
  int g = blockIdx.x*256 + threadIdx.x;
  if (g == 0) *total = 0;
  if (g >= n) return;
  int c = 0;
  for (int e = head[g]; e != -1; e = next[e]) ++c;
  cnt[g] = c;
}

// ------------- block-scan -> start offsets (order-free segments) --------------
__global__ void csr_scan(const int* __restrict__ cnt, int* start, int* total, int n){
  __shared__ int s[256];
  __shared__ int base_s;
  int t = threadIdx.x;
  int g = blockIdx.x*256 + t;
  int v = (g < n) ? cnt[g] : 0;
  s[t] = v;
  __syncthreads();
  for (int off = 1; off < 256; off <<= 1){
    int x = (t >= off) ? s[t-off] : 0;
    __syncthreads();
    s[t] += x;
    __syncthreads();
  }
  if (t == 255) base_s = atomicAdd(total, s[255]);
  __syncthreads();
  if (g < n) start[g] = base_s + s[t] - v;
}

// ------------- per-node chain walk: sequential col fill -----------------------
__global__ void chain_fill(const int* __restrict__ head, const int* __restrict__ next,
                           const int* __restrict__ src, const int* __restrict__ start,
                           int* col, int n){
  int g = blockIdx.x*256 + threadIdx.x;
  if (g >= n) return;
  int p = start[g];
  for (int e = head[g]; e != -1; e = next[e])
    col[p++] = src[e];
}

// ---------------- MFMA GEMM 128x128 + fused al (layers 1,2) --------------------
__global__ __launch_bounds__(256) void gemm_al_mfma(
    const void* __restrict__ X, int xkind,   // 0 = external input, 1 = packed pairs
    const void* __restrict__ W, const void* __restrict__ Wsrc, const void* __restrict__ Wdst,
    const int* __restrict__ flagp,
    unsigned* __restrict__ H2, float* __restrict__ AL, float* __restrict__ AD,
    int n, int ntiles)
{
  __shared__ unsigned short WT[128*136];   // W^T bf16, stride 136 (bank-stagger)
  const int isbf = *flagp;
  const int t = threadIdx.x;
  if (isbf){
    const unsigned short* W16 = (const unsigned short*)W;
    for (int idx = t; idx < 16384; idx += 256){
      int k = idx >> 7, nn = idx & 127;
      WT[nn*136 + k] = W16[idx];
    }
  } else {
    const float* Wf = (const float*)W;
    for (int idx = t; idx < 16384; idx += 256){
      int k = idx >> 7, nn = idx & 127;
      WT[nn*136 + k] = (unsigned short)(pk(Wf[idx], 0.f) & 0xffffu);
    }
  }
  __syncthreads();
  const int w = t >> 6;          // wave == head
  const int lane = t & 63;
  const int m = lane & 15, quad = lane >> 4;

  frag8 bf[4][2];
  #pragma unroll
  for (int s = 0; s < 4; ++s)
    #pragma unroll
    for (int ct = 0; ct < 2; ++ct){
      int colc = w*32 + ct*16 + m;
      int k0 = s*32 + quad*8;
      U4F8 v; v.u = *((const uint4*)&WT[colc*136 + k0]);
      bf[s][ct] = v.f;
    }
  float avv[2], dvv[2];
  #pragma unroll
  for (int ct = 0; ct < 2; ++ct){
    int colc = w*32 + ct*16 + m;
    avv[ct] = ldf(Wsrc, colc, isbf);
    dvv[ct] = ldf(Wdst, colc, isbf);
  }
  const bool pairs = (xkind == 1) || isbf;  // bf16 rows == packed-pair layout

  for (int tile = blockIdx.x; tile < ntiles; tile += gridDim.x){
    const int mb = tile*16;
    int nodeA = mb + m; if (nodeA >= n) nodeA = n - 1;
    frag8 af[4];
    #pragma unroll
    for (int s = 0; s < 4; ++s){
      int k0 = s*32 + quad*8;
      af[s] = pairs ? load_a_pairs((const unsigned*)X, nodeA, k0)
                    : load_a_f32((const float*)X, nodeA, k0);
    }
    f32x4 acc0 = {0.f,0.f,0.f,0.f}, acc1 = {0.f,0.f,0.f,0.f};
    #pragma unroll
    for (int s = 0; s < 4; ++s){
      acc0 = __builtin_amdgcn_mfma_f32_16x16x32_bf16(af[s], bf[s][0], acc0, 0,0,0);
      acc1 = __builtin_amdgcn_mfma_f32_16x16x32_bf16(af[s], bf[s][1], acc1, 0,0,0);
    }
    #pragma unroll
    for (int r = 0; r < 4; ++r){
      int g = mb + quad*4 + r;
      float v0 = acc0[r], v1 = acc1[r];
      unsigned u0 = pk(v0, __shfl_xor(v0, 1));
      unsigned u1 = pk(v1, __shfl_xor(v1, 1));
      bool ok = g < n;
      if (((lane & 1) == 0) && ok){
        H2[(size_t)g*64 + w*16 + (m >> 1)]     = u0;
        H2[(size_t)g*64 + w*16 + 8 + (m >> 1)] = u1;
      }
      float s1 = v0*avv[0] + v1*avv[1];
      float s2 = v0*dvv[0] + v1*dvv[1];
      s1 += __shfl_xor(s1,1); s1 += __shfl_xor(s1,2); s1 += __shfl_xor(s1,4); s1 += __shfl_xor(s1,8);
      s2 += __shfl_xor(s2,1); s2 += __shfl_xor(s2,2); s2 += __shfl_xor(s2,4); s2 += __shfl_xor(s2,8);
      if (m == 0 && ok){ AL[g*4 + w] = s1; AD[g*4 + w] = s2; }
    }
  }
}

// ---------------- MFMA GEMM 128x40 + fused al (layer 3) -----------------------
__global__ __launch_bounds__(256) void gemm3_mfma(
    const unsigned* __restrict__ X2, const void* __restrict__ W,
    const void* __restrict__ Wsrc, const void* __restrict__ Wdst,
    const int* __restrict__ flagp,
    unsigned* __restrict__ H3, float* __restrict__ AL, float* __restrict__ AD,
    int n, int ntiles)
{
  __shared__ unsigned short WT[48*136];
  const int isbf = *flagp;
  const int t = threadIdx.x;
  for (int idx = t; idx < 128*64; idx += 256){
    int c = idx & 63, k = idx >> 6;
    if (c < 48){
      unsigned short v = 0;
      if (c < 40){
        if (isbf) v = ((const unsigned short*)W)[k*40 + c];
        else      v = (unsigned short)(pk(((const float*)W)[k*40 + c], 0.f) & 0xffffu);
      }
      WT[c*136 + k] = v;
    }
  }
  __syncthreads();
  const int w = t >> 6;
  const int lane = t & 63;
  const int m = lane & 15, quad = lane >> 4;

  frag8 bf[4][3];
  float avv[3], dvv[3];
  #pragma unroll
  for (int ct = 0; ct < 3; ++ct){
    int colc = ct*16 + m;
    #pragma unroll
    for (int s = 0; s < 4; ++s){
      int k0 = s*32 + quad*8;
      U4F8 v; v.u = *((const uint4*)&WT[colc*136 + k0]);
      bf[s][ct] = v.f;
    }
    avv[ct] = (colc < 40) ? ldf(Wsrc, colc, isbf) : 0.f;
    dvv[ct] = (colc < 40) ? ldf(Wdst, colc, isbf) : 0.f;
  }

  for (int tg = blockIdx.x; tg*4 < ntiles; tg += gridDim.x){
    const int tile = tg*4 + w;
    if (tile >= ntiles) continue;
    const int mb = tile*16;
    int nodeA = mb + m; if (nodeA >= n) nodeA = n - 1;
    frag8 af[4];
    #pragma unroll
    for (int s = 0; s < 4; ++s)
      af[s] = load_a_pairs(X2, nodeA, s*32 + quad*8);
    f32x4 acc[3];
    #pragma unroll
    for (int ct = 0; ct < 3; ++ct) acc[ct] = (f32x4){0.f,0.f,0.f,0.f};
    #pragma unroll
    for (int s = 0; s < 4; ++s){
      acc[0] = __builtin_amdgcn_mfma_f32_16x16x32_bf16(af[s], bf[s][0], acc[0], 0,0,0);
      acc[1] = __builtin_amdgcn_mfma_f32_16x16x32_bf16(af[s], bf[s][1], acc[1], 0,0,0);
      acc[2] = __builtin_amdgcn_mfma_f32_16x16x32_bf16(af[s], bf[s][2], acc[2], 0,0,0);
    }
    #pragma unroll
    for (int r = 0; r < 4; ++r){
      int g = mb + quad*4 + r;
      bool ok = g < n;
      float ps = 0.f, pd = 0.f;
      #pragma unroll
      for (int ct = 0; ct < 3; ++ct){
        float v = acc[ct][r];
        ps += v*avv[ct]; pd += v*dvv[ct];
        unsigned u = pk(v, __shfl_xor(v, 1));
        bool stok = ((lane & 1) == 0) && ok && (ct < 2 || m < 8);
        if (stok) H3[(size_t)g*20 + ct*8 + (m >> 1)] = u;
      }
      ps += __shfl_xor(ps,1); ps += __shfl_xor(ps,2); ps += __shfl_xor(ps,4); ps += __shfl_xor(ps,8);
      pd += __shfl_xor(pd,1); pd += __shfl_xor(pd,2); pd += __shfl_xor(pd,4); pd += __shfl_xor(pd,8);
      if (m == 0 && ok){ AL[g] = ps; AD[g] = pd; }
    }
  }
}

// ---------------- aggregation (layers 1,2): wave/node, 8-wide edge unroll ------
__global__ __launch_bounds__(256) void agg4(
    const unsigned* __restrict__ H2,
    const float* __restrict__ ALf, const float* __restrict__ ADf,
    const int* __restrict__ cnt, const int* __restrict__ start, const int* __restrict__ col,
    const void* __restrict__ bias, const void* __restrict__ bng, const void* __restrict__ bnb,
    const void* __restrict__ bnm,  const void* __restrict__ bnv,
    const int* __restrict__ flagp,
    unsigned* __restrict__ Hout, int n)
{
  const int isbf = *flagp;
  const int wave = threadIdx.x >> 6;
  const int lane = threadIdx.x & 63;
  const int node = blockIdx.x*4 + wave;
  if (node >= n) return;
  const int head = lane >> 4;
  const float ad = ADf[node*4 + head];
  const int base = start[node], deg = cnt[node];

  float accL, accH, l;
  {
    float e = __expf(lrelu(ALf[node*4 + head] + ad));
    unsigned h = H2[(size_t)node*64 + lane];
    l = e; accL = e * bflo(h); accH = e * bfhi(h);
  }

  int i = 0;
  for (; i + 8 <= deg; i += 8){
    int sv[8]; float av[8]; unsigned hv[8];
    #pragma unroll
    for (int u = 0; u < 8; ++u){
      int s = col[base + i + u];
      sv[u] = ((unsigned)s < (unsigned)n) ? s : 0;
    }
    #pragma unroll
    for (int u = 0; u < 8; ++u) av[u] = ALf[sv[u]*4 + head];
    #pragma unroll
    for (int u = 0; u < 8; ++u) hv[u] = H2[(size_t)sv[u]*64 + lane];
    #pragma unroll
    for (int u = 0; u < 8; ++u){
      float e = __expf(lrelu(av[u] + ad));
      l    += e;
      accL += e * bflo(hv[u]);
      accH += e * bfhi(hv[u]);
    }
  }
  for (; i < deg; ++i){
    int s = col[base + i];
    if ((unsigned)s >= (unsigned)n) s = 0;
    float a = ALf[s*4 + head];
    unsigned h = H2[(size_t)s*64 + lane];
    float e = __expf(lrelu(a + ad));
    l += e; accL += e * bflo(h); accH += e * bfhi(h);
  }

  const float rl = 1.f / l;
  const int c0 = 2*lane, c1 = c0 + 1;
  float v0 = fmaxf(accL*rl + ldf(bias,c0,isbf), 0.f);
  v0 = (v0 - ldf(bnm,c0,isbf)) * rsqrtf(ldf(bnv,c0,isbf) + BN_EPS) * ldf(bng,c0,isbf) + ldf(bnb,c0,isbf);
  float v1 = fmaxf(accH*rl + ldf(bias,c1,isbf), 0.f);
  v1 = (v1 - ldf(bnm,c1,isbf)) * rsqrtf(ldf(bnv,c1,isbf) + BN_EPS) * ldf(bng,c1,isbf) + ldf(bnb,c1,isbf);
  Hout[(size_t)node*64 + lane] = pk(v0, v1);
}

// ---------------- aggregation (layer 3) + log_softmax -------------------------
__global__ __launch_bounds__(256) void agg1(
    const unsigned* __restrict__ H3,
    const float* __restrict__ AL, const float* __restrict__ AD,
    const int* __restrict__ cnt, const int* __restrict__ start, const int* __restrict__ col,
    const void* __restrict__ b3, const int* __restrict__ flagp,
    void* __restrict__ out, int n)
{
  const int isbf = *flagp;
  const int wave = threadIdx.x >> 6;
  const int lane = threadIdx.x & 63;
  const int node = blockIdx.x*4 + wave;
  if (node >= n) return;
  const float ad = AD[node];
  const bool act = lane < 20;
  const int base = start[node], deg = cnt[node];

  float accL, accH, l;
  {
    float e = __expf(lrelu(AL[node] + ad));
    unsigned h = act ? H3[(size_t)node*20 + lane] : 0u;
    l = e; accL = e * bflo(h); accH = e * bfhi(h);
  }

  int i = 0;
  for (; i + 8 <= deg; i += 8){
    int sv[8]; float av[8]; unsigned hv[8];
    #pragma unroll
    for (int u = 0; u < 8; ++u){
      int s = col[base + i + u];
      sv[u] = ((unsigned)s < (unsigned)n) ? s : 0;
    }
    #pragma unroll
    for (int u = 0; u < 8; ++u) av[u] = AL[sv[u]];
    #pragma unroll
    for (int u = 0; u < 8; ++u) hv[u] = act ? H3[(size_t)sv[u]*20 + lane] : 0u;
    #pragma unroll
    for (int u = 0; u < 8; ++u){
      float e = __expf(lrelu(av[u] + ad));
      l    += e;
      accL += e * bflo(hv[u]);
      accH += e * bfhi(hv[u]);
    }
  }
  for (; i < deg; ++i){
    int s = col[base + i];
    if ((unsigned)s >= (unsigned)n) s = 0;
    float a = AL[s];
    unsigned h = act ? H3[(size_t)s*20 + lane] : 0u;
    float e = __expf(lrelu(a + ad));
    l += e; accL += e * bflo(h); accH += e * bfhi(h);
  }

  const float rl = 1.f / l;
  const int c0 = 2*lane;
  float z0 = act ? (accL*rl + ldf(b3, c0,     isbf)) : NEGBIG;
  float z1 = act ? (accH*rl + ldf(b3, c0 + 1, isbf)) : NEGBIG;
  float mx = fmaxf(z0, z1);
  #pragma unroll
  for (int off = 1; off < 64; off <<= 1) mx = fmaxf(mx, __shfl_xor(mx, off));
  float p = act ? (__expf(z0 - mx) + __expf(z1 - mx)) : 0.f;
  float sum = p;
  #pragma unroll
  for (int off = 1; off < 64; off <<= 1) sum += __shfl_xor(sum, off);
  if (act){
    float lg = __logf(sum);
    float r0 = z0 - mx - lg, r1 = z1 - mx - lg;
    if (isbf) ((unsigned*)out)[(size_t)node*20 + lane] = pk(r0, r1);
    else      ((float2*)out)[(size_t)node*20 + lane] = make_float2(r0, r1);
  }
}

// ---------------- launch ----------------
extern "C" void kernel_launch(void* const* d_in, const int* in_sizes, int n_in,
                              void* d_out, int out_size, void* d_ws, size_t ws_size,
                              hipStream_t stream)
{
  (void)n_in; (void)out_size; (void)ws_size;
  const void* x    = d_in[0];
  const int*  ei   = (const int*)d_in[1];
  const void* W1   = d_in[2];
  const void* as1  = d_in[3];
  const void* ad1  = d_in[4];
  const void* b1   = d_in[5];
  const void* W2   = d_in[6];
  const void* as2  = d_in[7];
  const void* ad2  = d_in[8];
  const void* b2   = d_in[9];
  const void* W3   = d_in[10];
  const void* as3  = d_in[11];
  const void* ad3  = d_in[12];
  const void* b3   = d_in[13];
  const void* bn1g = d_in[14];
  const void* bn1b = d_in[15];
  const void* bn1m = d_in[16];
  const void* bn1v = d_in[17];
  const void* bn2g = d_in[18];
  const void* bn2b = d_in[19];
  const void* bn2m = d_in[20];
  const void* bn2v = d_in[21];

  const int N  = in_sizes[0] / 128;
  const int E  = in_sizes[1] / 2;
  const int ntiles = (N + 15) / 16;

  char* w = (char*)d_ws;
  size_t off = 0;
  auto alloc = [&](size_t bytes)->char*{
    char* p = w + off; off = (off + bytes + 255) & ~(size_t)255; return p;
  };
  unsigned* H2A = (unsigned*)alloc((size_t)N*64*4);   // packed bf16 pairs
  unsigned* H2B = (unsigned*)alloc((size_t)N*64*4);
  unsigned* H3p = (unsigned*)alloc((size_t)N*20*4);
  float* AL   = (float*)alloc((size_t)N*4*4);
  float* AD   = (float*)alloc((size_t)N*4*4);
  int*   headp = (int*)alloc((size_t)N*4);
  int*   nextp = (int*)alloc((size_t)E*4);
  int*   cnt   = (int*)alloc((size_t)N*4);
  int*   start = (int*)alloc((size_t)N*4);
  int*   col   = (int*)alloc((size_t)E*4);
  int*   flag  = (int*)alloc(256);
  int*   total = (int*)alloc(256);

  const int* srcp = ei;
  const int* dstp = ei + E;

  const int nb256 = (N + 255)/256, eb256 = (E + 255)/256;
  const int bb = (N + 3)/4;
  int g1 = ntiles < 625 ? ntiles : 625;
  int g3 = (ntiles + 3)/4; if (g3 > 400) g3 = 400;

  // CSR build via atomic linked lists (no scattered col writes)
  init_detect<<<nb256,256,0,stream>>>(headp, (const unsigned short*)W1, flag, N);
  chain_build<<<eb256,256,0,stream>>>(dstp, headp, nextp, E, N);
  chain_count<<<nb256,256,0,stream>>>(headp, nextp, cnt, total, N);
  csr_scan  <<<nb256,256,0,stream>>>(cnt, start, total, N);
  chain_fill<<<nb256,256,0,stream>>>(headp, nextp, srcp, start, col, N);

  // layer 1
  gemm_al_mfma<<<g1,256,0,stream>>>(x, 0, W1, as1, ad1, flag, H2A, AL, AD, N, ntiles);
  agg4<<<bb,256,0,stream>>>(H2A, AL, AD, cnt, start, col,
                            b1, bn1g, bn1b, bn1m, bn1v, flag, H2B, N);
  // layer 2
  gemm_al_mfma<<<g1,256,0,stream>>>(H2B, 1, W2, as2, ad2, flag, H2A, AL, AD, N, ntiles);
  agg4<<<bb,256,0,stream>>>(H2A, AL, AD, cnt, start, col,
                            b2, bn2g, bn2b, bn2m, bn2v, flag, H2B, N);
  // layer 3
  gemm3_mfma<<<g3,256,0,stream>>>(H2B, W3, as3, ad3, flag, H3p, AL, AD, N, ntiles);
  agg1<<<bb,256,0,stream>>>(H3p, AL, AD, cnt, start, col, b3, flag, d_out, N);
}